// Round 7
// baseline (1726.047 us; speedup 1.0000x reference)
//
#include <hip/hip_runtime.h>
#include <math.h>

// Swin-3D basic layer, bf16-MFMA: [LN1] [QKV] [attn] [proj+LN2] [FC1+gelu] [FC2+res]
// S=32,H=64,W=64, C=192, NH=6, HD=32, win 4x4x4 (N=64), shift 2, NWIN=2048, L=131072.
// Round 7: MLP un-fused (round-4 proven structure) + reg-staged prefetch in
// qkv/fc1/fc2 chunk loops (issue-early, write-late).

#define L_TOK 131072
#define C_DIM 192
#define NWIN 2048

typedef unsigned int uint32;
typedef unsigned short u16;
typedef __bf16 bf16x8 __attribute__((ext_vector_type(8)));
typedef __bf16 bf16x4 __attribute__((ext_vector_type(4)));
typedef float f32x4 __attribute__((ext_vector_type(4)));

__device__ __forceinline__ u16 f2bf(float f) {
    uint32 u = __float_as_uint(f);
    u += 0x7fffu + ((u >> 16) & 1u);
    return (u16)(u >> 16);
}
__device__ __forceinline__ float bf2f(u16 h) { return __uint_as_float(((uint32)h) << 16); }

// exact-erf gelu via Abramowitz-Stegun 7.1.26 (|err| <= 1.5e-7)
__device__ __forceinline__ float gelu_f(float x) {
    const float ax = fabsf(x) * 0.7071067811865475f;
    const float t = 1.0f / fmaf(0.3275911f, ax, 1.0f);
    float poly = fmaf(1.061405429f, t, -1.453152027f);
    poly = fmaf(poly, t, 1.421413741f);
    poly = fmaf(poly, t, -0.284496736f);
    poly = fmaf(poly, t, 0.254829592f);
    poly *= t;
    float erfv = 1.0f - poly * __expf(-ax * ax);
    erfv = (x < 0.0f) ? -erfv : erfv;
    return 0.5f * x * (1.0f + erfv);
}

// window-ordered row r -> natural token index (rolled[g] = orig[(g+shift)%D])
__device__ __forceinline__ int win_row_to_token(int r, int shifted) {
    const int win = r >> 6, n = r & 63;
    const int sb = win >> 8, hb = (win >> 4) & 15, wb = win & 15;
    int gz = sb * 4 + (n >> 4);
    int gy = hb * 4 + ((n >> 2) & 3);
    int gx = wb * 4 + (n & 3);
    if (shifted) { gz = (gz + 2) & 31; gy = (gy + 2) & 63; gx = (gx + 2) & 63; }
    return (gz << 12) | (gy << 6) | gx;
}

// ---------------------------------------------------------------------------
// weight transpose + bf16 convert: in [K][N] fp32 -> out [N][K] bf16
// ---------------------------------------------------------------------------
__global__ __launch_bounds__(256) void wtrans_kernel(const float* __restrict__ in,
                                                     u16* __restrict__ out, int K, int N) {
    const int idx = blockIdx.x * 256 + threadIdx.x;
    if (idx < K * N) {
        const int n = idx / K, k = idx - n * K;
        out[idx] = f2bf(in[(size_t)k * N + n]);
    }
}

// ---------------------------------------------------------------------------
// LayerNorm (block entry): fp32 in -> bf16 out, window partition (+shift)
// ---------------------------------------------------------------------------
__global__ __launch_bounds__(256) void ln_kernel(const float* __restrict__ x,
                                                 const float* __restrict__ g,
                                                 const float* __restrict__ b,
                                                 u16* __restrict__ out, int mode) {
    const int r = blockIdx.x * 4 + (threadIdx.x >> 6);
    const int lane = threadIdx.x & 63;
    const int tin = win_row_to_token(r, mode);
    const float* xr = x + (size_t)tin * C_DIM;
    const float v0 = xr[lane], v1 = xr[lane + 64], v2 = xr[lane + 128];
    float s = v0 + v1 + v2;
#pragma unroll
    for (int off = 32; off >= 1; off >>= 1) s += __shfl_xor(s, off, 64);
    const float mu = s * (1.0f / 192.0f);
    const float d0 = v0 - mu, d1 = v1 - mu, d2 = v2 - mu;
    float sq = d0 * d0 + d1 * d1 + d2 * d2;
#pragma unroll
    for (int off = 32; off >= 1; off >>= 1) sq += __shfl_xor(sq, off, 64);
    const float rstd = rsqrtf(sq * (1.0f / 192.0f) + 1e-5f);
    u16* orow = out + (size_t)r * C_DIM;
    orow[lane]       = f2bf(d0 * rstd * g[lane]       + b[lane]);
    orow[lane + 64]  = f2bf(d1 * rstd * g[lane + 64]  + b[lane + 64]);
    orow[lane + 128] = f2bf(d2 * rstd * g[lane + 128] + b[lane + 128]);
}

// ---------------------------------------------------------------------------
// staging helpers for K=192 tiles (LDS row stride 200 u16)
// ---------------------------------------------------------------------------
__device__ __forceinline__ void stage_rows192(const u16* __restrict__ g, u16* __restrict__ s,
                                              int iters) {
    const int tid = threadIdx.x;
#pragma unroll
    for (int i = 0; i < iters; ++i) {
        const int c = tid + 256 * i;
        const int row = c / 24, ko = (c - row * 24) * 8;
        *(uint4*)(s + row * 200 + ko) = *(const uint4*)(g + (size_t)row * 192 + ko);
    }
}

// 64x192 B tile: 6 uint4 per thread; load-to-regs / write-to-LDS split
__device__ __forceinline__ void loadB_regs(const u16* __restrict__ g, uint4 (&r)[6]) {
    const int tid = threadIdx.x;
#pragma unroll
    for (int i = 0; i < 6; ++i) {
        const int c = tid + 256 * i;
        const int row = c / 24, ko = (c - row * 24) * 8;
        r[i] = *(const uint4*)(g + (size_t)row * 192 + ko);
    }
}
__device__ __forceinline__ void writeB_lds(u16* __restrict__ s, const uint4 (&r)[6]) {
    const int tid = threadIdx.x;
#pragma unroll
    for (int i = 0; i < 6; ++i) {
        const int c = tid + 256 * i;
        const int row = c / 24, ko = (c - row * 24) * 8;
        *(uint4*)(s + row * 200 + ko) = r[i];
    }
}

__device__ __forceinline__ void compute192(const u16* __restrict__ As, const u16* __restrict__ Bs,
                                           f32x4 (&acc)[2][4]) {
    const int lane = threadIdx.x & 63, wave = threadIdx.x >> 6;
    const u16* pa = As + (wave * 32 + (lane & 15)) * 200 + ((lane >> 4) * 8);
    const u16* pb = Bs + (lane & 15) * 200 + ((lane >> 4) * 8);
#pragma unroll
    for (int ks = 0; ks < 6; ++ks) {
        const bf16x8 a0 = *(const bf16x8*)(pa + ks * 32);
        const bf16x8 a1 = *(const bf16x8*)(pa + 16 * 200 + ks * 32);
#pragma unroll
        for (int nj = 0; nj < 4; ++nj) {
            const bf16x8 b = *(const bf16x8*)(pb + nj * 16 * 200 + ks * 32);
            acc[0][nj] = __builtin_amdgcn_mfma_f32_16x16x32_bf16(a0, b, acc[0][nj], 0, 0, 0);
            acc[1][nj] = __builtin_amdgcn_mfma_f32_16x16x32_bf16(a1, b, acc[1][nj], 0, 0, 0);
        }
    }
}

// ---------------------------------------------------------------------------
// QKV: xw[M][192]bf16 @ qwT[576][192] -> q,k,v bf16 [win*6+head][64][32], q scaled
// ---------------------------------------------------------------------------
__global__ __launch_bounds__(256) void qkv_mfma(const u16* __restrict__ xw,
                                                const u16* __restrict__ qwT,
                                                const float* __restrict__ qb,
                                                u16* __restrict__ q, u16* __restrict__ k,
                                                u16* __restrict__ v) {
    __shared__ __align__(16) u16 As[128 * 200];
    __shared__ __align__(16) u16 Bs[64 * 200];
    const int m0 = blockIdx.x * 128;
    const int lane = threadIdx.x & 63, wave = threadIdx.x >> 6;
    stage_rows192(xw + (size_t)m0 * 192, As, 12);
    uint4 rb[6];
    loadB_regs(qwT, rb);
#pragma unroll 1
    for (int nc = 0; nc < 9; ++nc) {
        writeB_lds(Bs, rb);
        __syncthreads();
        if (nc < 8) loadB_regs(qwT + (size_t)(nc + 1) * 64 * 192, rb);
        f32x4 acc[2][4] = {};
        compute192(As, Bs, acc);
#pragma unroll
        for (int nj = 0; nj < 4; ++nj) {
            const int n = nc * 64 + nj * 16 + (lane & 15);
            const int which = n / 192;
            const int hn = n - which * 192;
            const int head = hn >> 5, hd = hn & 31;
            u16* dst = (which == 0) ? q : (which == 1) ? k : v;
            const float sc = (which == 0) ? 0.17677669529663687f : 1.0f;
            const float bi = qb[n];
#pragma unroll
            for (int mi = 0; mi < 2; ++mi)
#pragma unroll
                for (int r = 0; r < 4; ++r) {
                    const int m = m0 + wave * 32 + mi * 16 + ((lane >> 4) << 2) + r;
                    const int win = m >> 6, tok = m & 63;
                    dst[((size_t)(win * 6 + head) * 64 + tok) * 32 + hd] =
                        f2bf((acc[mi][nj][r] + bi) * sc);
                }
        }
        __syncthreads();
    }
}

// ---------------------------------------------------------------------------
// MFMA attention: one block per (win, head), 4 waves. Swapped QK^T.
// ---------------------------------------------------------------------------
__global__ __launch_bounds__(256) void attn_mfma(const u16* __restrict__ qg,
                                                 const u16* __restrict__ kg,
                                                 const u16* __restrict__ vg,
                                                 const float* __restrict__ rpb,
                                                 u16* __restrict__ o, int shifted) {
    __shared__ __align__(16) u16 vt[32 * 68];
    __shared__ __align__(16) u16 ps[64 * 68];
    __shared__ __align__(16) u16 os[64 * 40];
    __shared__ float bias_s[343];
    __shared__ int ms[64];
    const int tid = threadIdx.x;
    const int lane = tid & 63, w = tid >> 6;
    const int i = lane & 15, g = lane >> 4;
    const int head = blockIdx.x >> 11;
    const int win = blockIdx.x & 2047;
    const size_t base = (size_t)(win * 6 + head) * 2048;

    const bf16x8 qf = *(const bf16x8*)(qg + base + (size_t)(16 * w + i) * 32 + 8 * g);
    bf16x8 kf[4];
#pragma unroll
    for (int t = 0; t < 4; ++t)
        kf[t] = *(const bf16x8*)(kg + base + (size_t)(16 * t + i) * 32 + 8 * g);
    {
        const int n = tid >> 2, c0 = (tid & 3) * 8;
        uint4 raw = *(const uint4*)(vg + base + (size_t)n * 32 + c0);
        const u16* pr = (const u16*)&raw;
#pragma unroll
        for (int j = 0; j < 8; ++j) vt[(c0 + j) * 68 + n] = pr[j];
    }
    for (int idx = tid; idx < 343; idx += 256) bias_s[idx] = rpb[idx * 6 + head];
    if (tid < 64) {
        int mv = 0;
        if (shifted) {
            const int sb = win >> 8, hb = (win >> 4) & 15, wb = win & 15;
            const int gz = sb * 4 + (tid >> 4);
            const int gy = hb * 4 + ((tid >> 2) & 3);
            const int gx = wb * 4 + (tid & 3);
            const int rz = gz < 28 ? 0 : (gz < 30 ? 1 : 2);
            const int ry = gy < 60 ? 0 : (gy < 62 ? 1 : 2);
            const int rw = gx < 60 ? 0 : (gx < 62 ? 1 : 2);
            mv = rz * 9 + ry * 3 + rw;
        }
        ms[tid] = mv;
    }
    __syncthreads();

    const f32x4 zero = {0.0f, 0.0f, 0.0f, 0.0f};
    f32x4 s[4];
#pragma unroll
    for (int t = 0; t < 4; ++t)
        s[t] = __builtin_amdgcn_mfma_f32_16x16x32_bf16(kf[t], qf, zero, 0, 0, 0);

    const int qrow = 16 * w + i;
    const int mq = ms[qrow];
    float p[16];
#pragma unroll
    for (int t = 0; t < 4; ++t)
#pragma unroll
        for (int r = 0; r < 4; ++r) {
            const int j = 16 * t + 4 * g + r;
            const int dz = (qrow >> 4) - (j >> 4) + 3;
            const int dy = ((qrow >> 2) & 3) - ((j >> 2) & 3) + 3;
            const int dx = (qrow & 3) - (j & 3) + 3;
            float val = s[t][r] + bias_s[dz * 49 + dy * 7 + dx];
            if (shifted && (mq != ms[j])) val -= 100.0f;
            p[t * 4 + r] = val;
        }
    float mx = -3.0e38f;
#pragma unroll
    for (int u = 0; u < 16; ++u) mx = fmaxf(mx, p[u]);
    mx = fmaxf(mx, __shfl_xor(mx, 16, 64));
    mx = fmaxf(mx, __shfl_xor(mx, 32, 64));
    float sum = 0.0f;
#pragma unroll
    for (int u = 0; u < 16; ++u) { p[u] = __expf(p[u] - mx); sum += p[u]; }
    sum += __shfl_xor(sum, 16, 64);
    sum += __shfl_xor(sum, 32, 64);
    const float inv = 1.0f / sum;

#pragma unroll
    for (int t = 0; t < 4; ++t) {
        ushort4 pk;
        pk.x = f2bf(p[t * 4 + 0]); pk.y = f2bf(p[t * 4 + 1]);
        pk.z = f2bf(p[t * 4 + 2]); pk.w = f2bf(p[t * 4 + 3]);
        *(ushort4*)(ps + (size_t)qrow * 68 + 16 * t + 4 * g) = pk;
    }

    f32x4 oacc[2] = {zero, zero};
#pragma unroll
    for (int kb = 0; kb < 2; ++kb) {
        const bf16x4 alo = *(const bf16x4*)(ps + (size_t)qrow * 68 + 8 * g + 32 * kb);
        const bf16x4 ahi = *(const bf16x4*)(ps + (size_t)qrow * 68 + 8 * g + 32 * kb + 4);
        const bf16x8 a = __builtin_shufflevector(alo, ahi, 0, 1, 2, 3, 4, 5, 6, 7);
#pragma unroll
        for (int ct = 0; ct < 2; ++ct) {
            const bf16x4 blo = *(const bf16x4*)(vt + (size_t)(i + 16 * ct) * 68 + 8 * g + 32 * kb);
            const bf16x4 bhi = *(const bf16x4*)(vt + (size_t)(i + 16 * ct) * 68 + 8 * g + 32 * kb + 4);
            const bf16x8 b = __builtin_shufflevector(blo, bhi, 0, 1, 2, 3, 4, 5, 6, 7);
            oacc[ct] = __builtin_amdgcn_mfma_f32_16x16x32_bf16(a, b, oacc[ct], 0, 0, 0);
        }
    }
#pragma unroll
    for (int ct = 0; ct < 2; ++ct)
#pragma unroll
        for (int r = 0; r < 4; ++r) {
            const float ov = oacc[ct][r] * __shfl(inv, 4 * g + r, 64);
            os[(16 * w + 4 * g + r) * 40 + i + 16 * ct] = f2bf(ov);
        }
    __syncthreads();
    {
        const int n = tid >> 2, c0 = (tid & 3) * 8;
        const uint4 val = *(const uint4*)(os + n * 40 + c0);
        *(uint4*)(o + (size_t)(win * 64 + n) * C_DIM + head * 32 + c0) = val;
    }
}

// ---------------------------------------------------------------------------
// proj + residual + LN2 fused: x2 = xin + o@pw + pb (fp32), x2n = LN(x2) bf16
// ---------------------------------------------------------------------------
__global__ __launch_bounds__(256) void proj_ln_mfma(const u16* __restrict__ o,
                                                    const u16* __restrict__ pwT,
                                                    const float* __restrict__ pb,
                                                    const float* xin,
                                                    const float* __restrict__ g2,
                                                    const float* __restrict__ b2,
                                                    float* x2, u16* __restrict__ x2n,
                                                    int shifted) {
    __shared__ __align__(16) u16 As[128 * 200];
    __shared__ __align__(16) u16 Bs[64 * 200];
    const int m0 = blockIdx.x * 128;
    const int lane = threadIdx.x & 63, wave = threadIdx.x >> 6;
    const int i = lane & 15, g = lane >> 4;
    stage_rows192(o + (size_t)m0 * 192, As, 12);
    f32x4 acc[2][12] = {};
#pragma unroll 1
    for (int nc = 0; nc < 3; ++nc) {
        stage_rows192(pwT + (size_t)nc * 64 * 192, Bs, 6);
        __syncthreads();
        const u16* pa = As + (wave * 32 + i) * 200 + 8 * g;
        const u16* pbs = Bs + i * 200 + 8 * g;
#pragma unroll
        for (int ks = 0; ks < 6; ++ks) {
            const bf16x8 a0 = *(const bf16x8*)(pa + ks * 32);
            const bf16x8 a1 = *(const bf16x8*)(pa + 16 * 200 + ks * 32);
#pragma unroll
            for (int nj = 0; nj < 4; ++nj) {
                const bf16x8 b = *(const bf16x8*)(pbs + nj * 16 * 200 + ks * 32);
                acc[0][nc * 4 + nj] = __builtin_amdgcn_mfma_f32_16x16x32_bf16(a0, b, acc[0][nc * 4 + nj], 0, 0, 0);
                acc[1][nc * 4 + nj] = __builtin_amdgcn_mfma_f32_16x16x32_bf16(a1, b, acc[1][nc * 4 + nj], 0, 0, 0);
            }
        }
        __syncthreads();
    }
    float bi[12], gv[12], bv[12];
#pragma unroll
    for (int nj = 0; nj < 12; ++nj) {
        const int n = nj * 16 + i;
        bi[nj] = pb[n]; gv[nj] = g2[n]; bv[nj] = b2[n];
    }
#pragma unroll
    for (int mi = 0; mi < 2; ++mi)
#pragma unroll
        for (int r = 0; r < 4; ++r) {
            const int m = m0 + wave * 32 + mi * 16 + 4 * g + r;
            const int t = win_row_to_token(m, shifted);
            const float* xr = xin + (size_t)t * C_DIM;
            float v[12];
            float s = 0.0f;
#pragma unroll
            for (int nj = 0; nj < 12; ++nj) {
                v[nj] = xr[nj * 16 + i] + bi[nj] + acc[mi][nj][r];
                s += v[nj];
            }
            s += __shfl_xor(s, 1, 64); s += __shfl_xor(s, 2, 64);
            s += __shfl_xor(s, 4, 64); s += __shfl_xor(s, 8, 64);
            const float mu = s * (1.0f / 192.0f);
            float sq = 0.0f;
#pragma unroll
            for (int nj = 0; nj < 12; ++nj) {
                const float d = v[nj] - mu;
                sq += d * d;
            }
            sq += __shfl_xor(sq, 1, 64); sq += __shfl_xor(sq, 2, 64);
            sq += __shfl_xor(sq, 4, 64); sq += __shfl_xor(sq, 8, 64);
            const float rstd = rsqrtf(sq * (1.0f / 192.0f) + 1e-5f);
            float* x2r = x2 + (size_t)t * C_DIM;
            u16* x2nr = x2n + (size_t)t * C_DIM;
#pragma unroll
            for (int nj = 0; nj < 12; ++nj) {
                x2r[nj * 16 + i] = v[nj];
                x2nr[nj * 16 + i] = f2bf((v[nj] - mu) * rstd * gv[nj] + bv[nj]);
            }
        }
}

// ---------------------------------------------------------------------------
// FC1 + gelu: h = gelu(x2n @ f1w + f1b), h bf16 [M][768].
// A-stationary; B-chunk prefetched to regs (issue-early / write-late).
// ---------------------------------------------------------------------------
__global__ __launch_bounds__(256) void fc1_mfma(const u16* __restrict__ x2n,
                                                const u16* __restrict__ f1wT,
                                                const float* __restrict__ f1b,
                                                u16* __restrict__ h) {
    __shared__ __align__(16) u16 As[128 * 200];
    __shared__ __align__(16) u16 Bs[64 * 200];
    const int m0 = blockIdx.x * 128;
    const int lane = threadIdx.x & 63, wave = threadIdx.x >> 6;
    stage_rows192(x2n + (size_t)m0 * 192, As, 12);
    uint4 rb[6];
    loadB_regs(f1wT, rb);
#pragma unroll 1
    for (int nc = 0; nc < 12; ++nc) {
        writeB_lds(Bs, rb);
        __syncthreads();
        if (nc < 11) loadB_regs(f1wT + (size_t)(nc + 1) * 64 * 192, rb);
        f32x4 acc[2][4] = {};
        compute192(As, Bs, acc);
#pragma unroll
        for (int nj = 0; nj < 4; ++nj) {
            const int n = nc * 64 + nj * 16 + (lane & 15);
            const float bi = f1b[n];
#pragma unroll
            for (int mi = 0; mi < 2; ++mi)
#pragma unroll
                for (int r = 0; r < 4; ++r) {
                    const int m = m0 + wave * 32 + mi * 16 + ((lane >> 4) << 2) + r;
                    h[(size_t)m * 768 + n] = f2bf(gelu_f(acc[mi][nj][r] + bi));
                }
        }
        __syncthreads();
    }
}

// ---------------------------------------------------------------------------
// FC2 + residual: out = x2 + h @ f2w + f2b (out may alias x2).
// K-loop BK=64 over 768; A/B chunks prefetched to regs (issue-early/write-late).
// ---------------------------------------------------------------------------
__global__ __launch_bounds__(256) void fc2_mfma(const u16* __restrict__ h,
                                                const u16* __restrict__ f2wT,
                                                const float* __restrict__ f2b,
                                                const float* x2, float* out) {
    __shared__ __align__(16) u16 As[128 * 72];
    __shared__ __align__(16) u16 Bs[192 * 72];
    const int tid = threadIdx.x, lane = tid & 63, wave = tid >> 6;
    const int m0 = blockIdx.x * 128;
    uint4 ra[4], rb[6];
    // load chunk 0
#pragma unroll
    for (int i = 0; i < 4; ++i) {
        const int c = tid + 256 * i, row = c >> 3, ko = (c & 7) * 8;
        ra[i] = *(const uint4*)(h + (size_t)(m0 + row) * 768 + ko);
    }
#pragma unroll
    for (int i = 0; i < 6; ++i) {
        const int c = tid + 256 * i, row = c >> 3, ko = (c & 7) * 8;
        rb[i] = *(const uint4*)(f2wT + (size_t)row * 768 + ko);
    }
    f32x4 acc[2][12] = {};
#pragma unroll 1
    for (int kc = 0; kc < 12; ++kc) {
#pragma unroll
        for (int i = 0; i < 4; ++i) {
            const int c = tid + 256 * i, row = c >> 3, ko = (c & 7) * 8;
            *(uint4*)(As + row * 72 + ko) = ra[i];
        }
#pragma unroll
        for (int i = 0; i < 6; ++i) {
            const int c = tid + 256 * i, row = c >> 3, ko = (c & 7) * 8;
            *(uint4*)(Bs + row * 72 + ko) = rb[i];
        }
        __syncthreads();
        if (kc < 11) {
            const int k0 = (kc + 1) * 64;
#pragma unroll
            for (int i = 0; i < 4; ++i) {
                const int c = tid + 256 * i, row = c >> 3, ko = (c & 7) * 8;
                ra[i] = *(const uint4*)(h + (size_t)(m0 + row) * 768 + k0 + ko);
            }
#pragma unroll
            for (int i = 0; i < 6; ++i) {
                const int c = tid + 256 * i, row = c >> 3, ko = (c & 7) * 8;
                rb[i] = *(const uint4*)(f2wT + (size_t)row * 768 + k0 + ko);
            }
        }
        const u16* pa = As + (wave * 32 + (lane & 15)) * 72 + (lane >> 4) * 8;
        const u16* pb = Bs + (lane & 15) * 72 + (lane >> 4) * 8;
#pragma unroll
        for (int ks = 0; ks < 2; ++ks) {
            const bf16x8 a0 = *(const bf16x8*)(pa + ks * 32);
            const bf16x8 a1 = *(const bf16x8*)(pa + 16 * 72 + ks * 32);
#pragma unroll
            for (int nj = 0; nj < 12; ++nj) {
                const bf16x8 b = *(const bf16x8*)(pb + nj * 16 * 72 + ks * 32);
                acc[0][nj] = __builtin_amdgcn_mfma_f32_16x16x32_bf16(a0, b, acc[0][nj], 0, 0, 0);
                acc[1][nj] = __builtin_amdgcn_mfma_f32_16x16x32_bf16(a1, b, acc[1][nj], 0, 0, 0);
            }
        }
        __syncthreads();
    }
#pragma unroll
    for (int nj = 0; nj < 12; ++nj) {
        const int n = nj * 16 + (lane & 15);
        const float bi = f2b[n];
#pragma unroll
        for (int mi = 0; mi < 2; ++mi)
#pragma unroll
            for (int r = 0; r < 4; ++r) {
                const int m = m0 + wave * 32 + mi * 16 + ((lane >> 4) << 2) + r;
                const size_t gi = (size_t)m * C_DIM + n;
                out[gi] = x2[gi] + bi + acc[mi][nj][r];
            }
    }
}

// ---------------------------------------------------------------------------
// orchestration. ws bytes (PB = 48MB): [0,PB) xw->o ; [PB,2PB) q ; [2PB,3PB) k ;
// [3PB,4PB) v ; h overlays [PB,5PB) after attn ; x2n [5PB,6PB) ; weights at 6PB.
// x2 = d_out fp32.
// ---------------------------------------------------------------------------
static void run_block(const float* X, float* XOUT,
                      const float* g1, const float* b1, const float* qb,
                      const float* rpb, const float* pb,
                      const float* g2, const float* b2,
                      const float* f1b, const float* f2b,
                      const u16* qwT, const u16* pwT, const u16* f1wT, const u16* f2wT,
                      int shifted, char* ws, hipStream_t stream) {
    const size_t PB = (size_t)L_TOK * C_DIM * sizeof(u16);  // 48 MB
    u16* xw  = (u16*)ws;
    u16* q   = (u16*)(ws + PB);
    u16* k   = (u16*)(ws + 2 * PB);
    u16* v   = (u16*)(ws + 3 * PB);
    u16* o   = xw;
    u16* h   = (u16*)(ws + PB);          // [PB,5PB): L x 768 bf16, overlays q,k,v
    u16* x2n = (u16*)(ws + 5 * PB);
    float* x2 = XOUT;

    ln_kernel<<<L_TOK / 4, 256, 0, stream>>>(X, g1, b1, xw, shifted ? 1 : 0);
    qkv_mfma<<<L_TOK / 128, 256, 0, stream>>>(xw, qwT, qb, q, k, v);
    attn_mfma<<<NWIN * 6, 256, 0, stream>>>(q, k, v, rpb, o, shifted);
    proj_ln_mfma<<<L_TOK / 128, 256, 0, stream>>>(o, pwT, pb, X, g2, b2, x2, x2n, shifted);
    fc1_mfma<<<L_TOK / 128, 256, 0, stream>>>(x2n, f1wT, f1b, h);
    fc2_mfma<<<L_TOK / 128, 256, 0, stream>>>(h, f2wT, f2b, x2, XOUT);
}

extern "C" void kernel_launch(void* const* d_in, const int* in_sizes, int n_in,
                              void* d_out, int out_size, void* d_ws, size_t ws_size,
                              hipStream_t stream) {
    const float* x = (const float*)d_in[0];
    float* out = (float*)d_out;
    char* ws = (char*)d_ws;
    auto in = [&](int i) { return (const float*)d_in[i]; };

    const size_t offW = (size_t)L_TOK * C_DIM * sizeof(u16) * 6;
    u16* wbase = (u16*)(ws + offW);
    const size_t SQ = 110592, SP = 36864, SF1 = 147456, SF2 = 147456;
    const size_t WBLK = SQ + SP + SF1 + SF2;
    u16* qwT[2]  = { wbase,                    wbase + WBLK };
    u16* pwT[2]  = { wbase + SQ,               wbase + WBLK + SQ };
    u16* f1wT[2] = { wbase + SQ + SP,          wbase + WBLK + SQ + SP };
    u16* f2wT[2] = { wbase + SQ + SP + SF1,    wbase + WBLK + SQ + SP + SF1 };

    wtrans_kernel<<<(192 * 576 + 255) / 256, 256, 0, stream>>>(in(3),  qwT[0],  192, 576);
    wtrans_kernel<<<(192 * 192 + 255) / 256, 256, 0, stream>>>(in(6),  pwT[0],  192, 192);
    wtrans_kernel<<<(192 * 768 + 255) / 256, 256, 0, stream>>>(in(10), f1wT[0], 192, 768);
    wtrans_kernel<<<(768 * 192 + 255) / 256, 256, 0, stream>>>(in(12), f2wT[0], 768, 192);
    wtrans_kernel<<<(192 * 576 + 255) / 256, 256, 0, stream>>>(in(16), qwT[1],  192, 576);
    wtrans_kernel<<<(192 * 192 + 255) / 256, 256, 0, stream>>>(in(19), pwT[1],  192, 192);
    wtrans_kernel<<<(192 * 768 + 255) / 256, 256, 0, stream>>>(in(23), f1wT[1], 192, 768);
    wtrans_kernel<<<(768 * 192 + 255) / 256, 256, 0, stream>>>(in(25), f2wT[1], 768, 192);

    run_block(x, out, in(1), in(2), in(4), in(5), in(7), in(8), in(9), in(11), in(13),
              qwT[0], pwT[0], f1wT[0], f2wT[0], 0, ws, stream);
    run_block(out, out, in(14), in(15), in(17), in(18), in(20), in(21), in(22), in(24), in(26),
              qwT[1], pwT[1], f1wT[1], f2wT[1], 1, ws, stream);
}

// Round 8
// 1332.240 us; speedup vs baseline: 1.2956x; 1.2956x over previous
//
#include <hip/hip_runtime.h>
#include <math.h>

// Swin-3D basic layer, bf16-MFMA: [LN1] [QKV] [attn] [proj+LN2] [FC1+gelu] [FC2+res]
// Round 8: revert reg-prefetch (caused scratch spills in fc2: VGPR 144, WRITE 246MB).
// = round-4 proven GEMM structure + proj_ln fusion + fast A&S gelu.

#define L_TOK 131072
#define C_DIM 192
#define NWIN 2048

typedef unsigned int uint32;
typedef unsigned short u16;
typedef __bf16 bf16x8 __attribute__((ext_vector_type(8)));
typedef __bf16 bf16x4 __attribute__((ext_vector_type(4)));
typedef float f32x4 __attribute__((ext_vector_type(4)));

__device__ __forceinline__ u16 f2bf(float f) {
    uint32 u = __float_as_uint(f);
    u += 0x7fffu + ((u >> 16) & 1u);
    return (u16)(u >> 16);
}
__device__ __forceinline__ float bf2f(u16 h) { return __uint_as_float(((uint32)h) << 16); }

// exact-erf gelu via Abramowitz-Stegun 7.1.26 (|err| <= 1.5e-7)
__device__ __forceinline__ float gelu_f(float x) {
    const float ax = fabsf(x) * 0.7071067811865475f;
    const float t = 1.0f / fmaf(0.3275911f, ax, 1.0f);
    float poly = fmaf(1.061405429f, t, -1.453152027f);
    poly = fmaf(poly, t, 1.421413741f);
    poly = fmaf(poly, t, -0.284496736f);
    poly = fmaf(poly, t, 0.254829592f);
    poly *= t;
    float erfv = 1.0f - poly * __expf(-ax * ax);
    erfv = (x < 0.0f) ? -erfv : erfv;
    return 0.5f * x * (1.0f + erfv);
}

// window-ordered row r -> natural token index (rolled[g] = orig[(g+shift)%D])
__device__ __forceinline__ int win_row_to_token(int r, int shifted) {
    const int win = r >> 6, n = r & 63;
    const int sb = win >> 8, hb = (win >> 4) & 15, wb = win & 15;
    int gz = sb * 4 + (n >> 4);
    int gy = hb * 4 + ((n >> 2) & 3);
    int gx = wb * 4 + (n & 3);
    if (shifted) { gz = (gz + 2) & 31; gy = (gy + 2) & 63; gx = (gx + 2) & 63; }
    return (gz << 12) | (gy << 6) | gx;
}

// ---------------------------------------------------------------------------
// weight transpose + bf16 convert: in [K][N] fp32 -> out [N][K] bf16
// ---------------------------------------------------------------------------
__global__ __launch_bounds__(256) void wtrans_kernel(const float* __restrict__ in,
                                                     u16* __restrict__ out, int K, int N) {
    const int idx = blockIdx.x * 256 + threadIdx.x;
    if (idx < K * N) {
        const int n = idx / K, k = idx - n * K;
        out[idx] = f2bf(in[(size_t)k * N + n]);
    }
}

// ---------------------------------------------------------------------------
// LayerNorm (block entry): fp32 in -> bf16 out, window partition (+shift)
// ---------------------------------------------------------------------------
__global__ __launch_bounds__(256) void ln_kernel(const float* __restrict__ x,
                                                 const float* __restrict__ g,
                                                 const float* __restrict__ b,
                                                 u16* __restrict__ out, int mode) {
    const int r = blockIdx.x * 4 + (threadIdx.x >> 6);
    const int lane = threadIdx.x & 63;
    const int tin = win_row_to_token(r, mode);
    const float* xr = x + (size_t)tin * C_DIM;
    const float v0 = xr[lane], v1 = xr[lane + 64], v2 = xr[lane + 128];
    float s = v0 + v1 + v2;
#pragma unroll
    for (int off = 32; off >= 1; off >>= 1) s += __shfl_xor(s, off, 64);
    const float mu = s * (1.0f / 192.0f);
    const float d0 = v0 - mu, d1 = v1 - mu, d2 = v2 - mu;
    float sq = d0 * d0 + d1 * d1 + d2 * d2;
#pragma unroll
    for (int off = 32; off >= 1; off >>= 1) sq += __shfl_xor(sq, off, 64);
    const float rstd = rsqrtf(sq * (1.0f / 192.0f) + 1e-5f);
    u16* orow = out + (size_t)r * C_DIM;
    orow[lane]       = f2bf(d0 * rstd * g[lane]       + b[lane]);
    orow[lane + 64]  = f2bf(d1 * rstd * g[lane + 64]  + b[lane + 64]);
    orow[lane + 128] = f2bf(d2 * rstd * g[lane + 128] + b[lane + 128]);
}

// ---------------------------------------------------------------------------
// staging helpers for K=192 tiles (LDS row stride 200 u16)
// ---------------------------------------------------------------------------
__device__ __forceinline__ void stage_rows192(const u16* __restrict__ g, u16* __restrict__ s,
                                              int iters) {
    const int tid = threadIdx.x;
#pragma unroll
    for (int i = 0; i < iters; ++i) {
        const int c = tid + 256 * i;
        const int row = c / 24, ko = (c - row * 24) * 8;
        *(uint4*)(s + row * 200 + ko) = *(const uint4*)(g + (size_t)row * 192 + ko);
    }
}

__device__ __forceinline__ void compute192(const u16* __restrict__ As, const u16* __restrict__ Bs,
                                           f32x4 (&acc)[2][4]) {
    const int lane = threadIdx.x & 63, wave = threadIdx.x >> 6;
    const u16* pa = As + (wave * 32 + (lane & 15)) * 200 + ((lane >> 4) * 8);
    const u16* pb = Bs + (lane & 15) * 200 + ((lane >> 4) * 8);
#pragma unroll
    for (int ks = 0; ks < 6; ++ks) {
        const bf16x8 a0 = *(const bf16x8*)(pa + ks * 32);
        const bf16x8 a1 = *(const bf16x8*)(pa + 16 * 200 + ks * 32);
#pragma unroll
        for (int nj = 0; nj < 4; ++nj) {
            const bf16x8 b = *(const bf16x8*)(pb + nj * 16 * 200 + ks * 32);
            acc[0][nj] = __builtin_amdgcn_mfma_f32_16x16x32_bf16(a0, b, acc[0][nj], 0, 0, 0);
            acc[1][nj] = __builtin_amdgcn_mfma_f32_16x16x32_bf16(a1, b, acc[1][nj], 0, 0, 0);
        }
    }
}

// ---------------------------------------------------------------------------
// QKV: xw[M][192]bf16 @ qwT[576][192] -> q,k,v bf16 [win*6+head][64][32], q scaled
// ---------------------------------------------------------------------------
__global__ __launch_bounds__(256) void qkv_mfma(const u16* __restrict__ xw,
                                                const u16* __restrict__ qwT,
                                                const float* __restrict__ qb,
                                                u16* __restrict__ q, u16* __restrict__ k,
                                                u16* __restrict__ v) {
    __shared__ __align__(16) u16 As[128 * 200];
    __shared__ __align__(16) u16 Bs[64 * 200];
    const int m0 = blockIdx.x * 128;
    const int lane = threadIdx.x & 63, wave = threadIdx.x >> 6;
    stage_rows192(xw + (size_t)m0 * 192, As, 12);
#pragma unroll 1
    for (int nc = 0; nc < 9; ++nc) {
        stage_rows192(qwT + (size_t)nc * 64 * 192, Bs, 6);
        __syncthreads();
        f32x4 acc[2][4] = {};
        compute192(As, Bs, acc);
#pragma unroll
        for (int nj = 0; nj < 4; ++nj) {
            const int n = nc * 64 + nj * 16 + (lane & 15);
            const int which = n / 192;
            const int hn = n - which * 192;
            const int head = hn >> 5, hd = hn & 31;
            u16* dst = (which == 0) ? q : (which == 1) ? k : v;
            const float sc = (which == 0) ? 0.17677669529663687f : 1.0f;
            const float bi = qb[n];
#pragma unroll
            for (int mi = 0; mi < 2; ++mi)
#pragma unroll
                for (int r = 0; r < 4; ++r) {
                    const int m = m0 + wave * 32 + mi * 16 + ((lane >> 4) << 2) + r;
                    const int win = m >> 6, tok = m & 63;
                    dst[((size_t)(win * 6 + head) * 64 + tok) * 32 + hd] =
                        f2bf((acc[mi][nj][r] + bi) * sc);
                }
        }
        __syncthreads();
    }
}

// ---------------------------------------------------------------------------
// MFMA attention: one block per (win, head), 4 waves. Swapped QK^T.
// ---------------------------------------------------------------------------
__global__ __launch_bounds__(256) void attn_mfma(const u16* __restrict__ qg,
                                                 const u16* __restrict__ kg,
                                                 const u16* __restrict__ vg,
                                                 const float* __restrict__ rpb,
                                                 u16* __restrict__ o, int shifted) {
    __shared__ __align__(16) u16 vt[32 * 68];
    __shared__ __align__(16) u16 ps[64 * 68];
    __shared__ __align__(16) u16 os[64 * 40];
    __shared__ float bias_s[343];
    __shared__ int ms[64];
    const int tid = threadIdx.x;
    const int lane = tid & 63, w = tid >> 6;
    const int i = lane & 15, g = lane >> 4;
    const int head = blockIdx.x >> 11;
    const int win = blockIdx.x & 2047;
    const size_t base = (size_t)(win * 6 + head) * 2048;

    const bf16x8 qf = *(const bf16x8*)(qg + base + (size_t)(16 * w + i) * 32 + 8 * g);
    bf16x8 kf[4];
#pragma unroll
    for (int t = 0; t < 4; ++t)
        kf[t] = *(const bf16x8*)(kg + base + (size_t)(16 * t + i) * 32 + 8 * g);
    {
        const int n = tid >> 2, c0 = (tid & 3) * 8;
        uint4 raw = *(const uint4*)(vg + base + (size_t)n * 32 + c0);
        const u16* pr = (const u16*)&raw;
#pragma unroll
        for (int j = 0; j < 8; ++j) vt[(c0 + j) * 68 + n] = pr[j];
    }
    for (int idx = tid; idx < 343; idx += 256) bias_s[idx] = rpb[idx * 6 + head];
    if (tid < 64) {
        int mv = 0;
        if (shifted) {
            const int sb = win >> 8, hb = (win >> 4) & 15, wb = win & 15;
            const int gz = sb * 4 + (tid >> 4);
            const int gy = hb * 4 + ((tid >> 2) & 3);
            const int gx = wb * 4 + (tid & 3);
            const int rz = gz < 28 ? 0 : (gz < 30 ? 1 : 2);
            const int ry = gy < 60 ? 0 : (gy < 62 ? 1 : 2);
            const int rw = gx < 60 ? 0 : (gx < 62 ? 1 : 2);
            mv = rz * 9 + ry * 3 + rw;
        }
        ms[tid] = mv;
    }
    __syncthreads();

    const f32x4 zero = {0.0f, 0.0f, 0.0f, 0.0f};
    f32x4 s[4];
#pragma unroll
    for (int t = 0; t < 4; ++t)
        s[t] = __builtin_amdgcn_mfma_f32_16x16x32_bf16(kf[t], qf, zero, 0, 0, 0);

    const int qrow = 16 * w + i;
    const int mq = ms[qrow];
    float p[16];
#pragma unroll
    for (int t = 0; t < 4; ++t)
#pragma unroll
        for (int r = 0; r < 4; ++r) {
            const int j = 16 * t + 4 * g + r;
            const int dz = (qrow >> 4) - (j >> 4) + 3;
            const int dy = ((qrow >> 2) & 3) - ((j >> 2) & 3) + 3;
            const int dx = (qrow & 3) - (j & 3) + 3;
            float val = s[t][r] + bias_s[dz * 49 + dy * 7 + dx];
            if (shifted && (mq != ms[j])) val -= 100.0f;
            p[t * 4 + r] = val;
        }
    float mx = -3.0e38f;
#pragma unroll
    for (int u = 0; u < 16; ++u) mx = fmaxf(mx, p[u]);
    mx = fmaxf(mx, __shfl_xor(mx, 16, 64));
    mx = fmaxf(mx, __shfl_xor(mx, 32, 64));
    float sum = 0.0f;
#pragma unroll
    for (int u = 0; u < 16; ++u) { p[u] = __expf(p[u] - mx); sum += p[u]; }
    sum += __shfl_xor(sum, 16, 64);
    sum += __shfl_xor(sum, 32, 64);
    const float inv = 1.0f / sum;

#pragma unroll
    for (int t = 0; t < 4; ++t) {
        ushort4 pk;
        pk.x = f2bf(p[t * 4 + 0]); pk.y = f2bf(p[t * 4 + 1]);
        pk.z = f2bf(p[t * 4 + 2]); pk.w = f2bf(p[t * 4 + 3]);
        *(ushort4*)(ps + (size_t)qrow * 68 + 16 * t + 4 * g) = pk;
    }

    f32x4 oacc[2] = {zero, zero};
#pragma unroll
    for (int kb = 0; kb < 2; ++kb) {
        const bf16x4 alo = *(const bf16x4*)(ps + (size_t)qrow * 68 + 8 * g + 32 * kb);
        const bf16x4 ahi = *(const bf16x4*)(ps + (size_t)qrow * 68 + 8 * g + 32 * kb + 4);
        const bf16x8 a = __builtin_shufflevector(alo, ahi, 0, 1, 2, 3, 4, 5, 6, 7);
#pragma unroll
        for (int ct = 0; ct < 2; ++ct) {
            const bf16x4 blo = *(const bf16x4*)(vt + (size_t)(i + 16 * ct) * 68 + 8 * g + 32 * kb);
            const bf16x4 bhi = *(const bf16x4*)(vt + (size_t)(i + 16 * ct) * 68 + 8 * g + 32 * kb + 4);
            const bf16x8 b = __builtin_shufflevector(blo, bhi, 0, 1, 2, 3, 4, 5, 6, 7);
            oacc[ct] = __builtin_amdgcn_mfma_f32_16x16x32_bf16(a, b, oacc[ct], 0, 0, 0);
        }
    }
#pragma unroll
    for (int ct = 0; ct < 2; ++ct)
#pragma unroll
        for (int r = 0; r < 4; ++r) {
            const float ov = oacc[ct][r] * __shfl(inv, 4 * g + r, 64);
            os[(16 * w + 4 * g + r) * 40 + i + 16 * ct] = f2bf(ov);
        }
    __syncthreads();
    {
        const int n = tid >> 2, c0 = (tid & 3) * 8;
        const uint4 val = *(const uint4*)(os + n * 40 + c0);
        *(uint4*)(o + (size_t)(win * 64 + n) * C_DIM + head * 32 + c0) = val;
    }
}

// ---------------------------------------------------------------------------
// proj + residual + LN2 fused: x2 = xin + o@pw + pb (fp32), x2n = LN(x2) bf16
// ---------------------------------------------------------------------------
__global__ __launch_bounds__(256) void proj_ln_mfma(const u16* __restrict__ o,
                                                    const u16* __restrict__ pwT,
                                                    const float* __restrict__ pb,
                                                    const float* xin,
                                                    const float* __restrict__ g2,
                                                    const float* __restrict__ b2,
                                                    float* x2, u16* __restrict__ x2n,
                                                    int shifted) {
    __shared__ __align__(16) u16 As[128 * 200];
    __shared__ __align__(16) u16 Bs[64 * 200];
    const int m0 = blockIdx.x * 128;
    const int lane = threadIdx.x & 63, wave = threadIdx.x >> 6;
    const int i = lane & 15, g = lane >> 4;
    stage_rows192(o + (size_t)m0 * 192, As, 12);
    f32x4 acc[2][12] = {};
#pragma unroll 1
    for (int nc = 0; nc < 3; ++nc) {
        stage_rows192(pwT + (size_t)nc * 64 * 192, Bs, 6);
        __syncthreads();
        const u16* pa = As + (wave * 32 + i) * 200 + 8 * g;
        const u16* pbs = Bs + i * 200 + 8 * g;
#pragma unroll
        for (int ks = 0; ks < 6; ++ks) {
            const bf16x8 a0 = *(const bf16x8*)(pa + ks * 32);
            const bf16x8 a1 = *(const bf16x8*)(pa + 16 * 200 + ks * 32);
#pragma unroll
            for (int nj = 0; nj < 4; ++nj) {
                const bf16x8 b = *(const bf16x8*)(pbs + nj * 16 * 200 + ks * 32);
                acc[0][nc * 4 + nj] = __builtin_amdgcn_mfma_f32_16x16x32_bf16(a0, b, acc[0][nc * 4 + nj], 0, 0, 0);
                acc[1][nc * 4 + nj] = __builtin_amdgcn_mfma_f32_16x16x32_bf16(a1, b, acc[1][nc * 4 + nj], 0, 0, 0);
            }
        }
        __syncthreads();
    }
    float bi[12], gv[12], bv[12];
#pragma unroll
    for (int nj = 0; nj < 12; ++nj) {
        const int n = nj * 16 + i;
        bi[nj] = pb[n]; gv[nj] = g2[n]; bv[nj] = b2[n];
    }
#pragma unroll
    for (int mi = 0; mi < 2; ++mi)
#pragma unroll
        for (int r = 0; r < 4; ++r) {
            const int m = m0 + wave * 32 + mi * 16 + 4 * g + r;
            const int t = win_row_to_token(m, shifted);
            const float* xr = xin + (size_t)t * C_DIM;
            float v[12];
            float s = 0.0f;
#pragma unroll
            for (int nj = 0; nj < 12; ++nj) {
                v[nj] = xr[nj * 16 + i] + bi[nj] + acc[mi][nj][r];
                s += v[nj];
            }
            s += __shfl_xor(s, 1, 64); s += __shfl_xor(s, 2, 64);
            s += __shfl_xor(s, 4, 64); s += __shfl_xor(s, 8, 64);
            const float mu = s * (1.0f / 192.0f);
            float sq = 0.0f;
#pragma unroll
            for (int nj = 0; nj < 12; ++nj) {
                const float d = v[nj] - mu;
                sq += d * d;
            }
            sq += __shfl_xor(sq, 1, 64); sq += __shfl_xor(sq, 2, 64);
            sq += __shfl_xor(sq, 4, 64); sq += __shfl_xor(sq, 8, 64);
            const float rstd = rsqrtf(sq * (1.0f / 192.0f) + 1e-5f);
            float* x2r = x2 + (size_t)t * C_DIM;
            u16* x2nr = x2n + (size_t)t * C_DIM;
#pragma unroll
            for (int nj = 0; nj < 12; ++nj) {
                x2r[nj * 16 + i] = v[nj];
                x2nr[nj * 16 + i] = f2bf((v[nj] - mu) * rstd * gv[nj] + bv[nj]);
            }
        }
}

// ---------------------------------------------------------------------------
// FC1 + gelu: h = gelu(x2n @ f1w + f1b), h bf16 [M][768]. A-stationary.
// ---------------------------------------------------------------------------
__global__ __launch_bounds__(256) void fc1_mfma(const u16* __restrict__ x2n,
                                                const u16* __restrict__ f1wT,
                                                const float* __restrict__ f1b,
                                                u16* __restrict__ h) {
    __shared__ __align__(16) u16 As[128 * 200];
    __shared__ __align__(16) u16 Bs[64 * 200];
    const int m0 = blockIdx.x * 128;
    const int lane = threadIdx.x & 63, wave = threadIdx.x >> 6;
    stage_rows192(x2n + (size_t)m0 * 192, As, 12);
#pragma unroll 1
    for (int nc = 0; nc < 12; ++nc) {
        stage_rows192(f1wT + (size_t)nc * 64 * 192, Bs, 6);
        __syncthreads();
        f32x4 acc[2][4] = {};
        compute192(As, Bs, acc);
#pragma unroll
        for (int nj = 0; nj < 4; ++nj) {
            const int n = nc * 64 + nj * 16 + (lane & 15);
            const float bi = f1b[n];
#pragma unroll
            for (int mi = 0; mi < 2; ++mi)
#pragma unroll
                for (int r = 0; r < 4; ++r) {
                    const int m = m0 + wave * 32 + mi * 16 + ((lane >> 4) << 2) + r;
                    h[(size_t)m * 768 + n] = f2bf(gelu_f(acc[mi][nj][r] + bi));
                }
        }
        __syncthreads();
    }
}

// ---------------------------------------------------------------------------
// FC2 + residual: out = x2 + h @ f2w + f2b (out may alias x2). K-loop BK=64.
// ---------------------------------------------------------------------------
__global__ __launch_bounds__(256) void fc2_mfma(const u16* __restrict__ h,
                                                const u16* __restrict__ f2wT,
                                                const float* __restrict__ f2b,
                                                const float* x2, float* out) {
    __shared__ __align__(16) u16 As[128 * 72];
    __shared__ __align__(16) u16 Bs[192 * 72];
    const int tid = threadIdx.x, lane = tid & 63, wave = tid >> 6;
    const int m0 = blockIdx.x * 128;
    f32x4 acc[2][12] = {};
#pragma unroll 1
    for (int kc = 0; kc < 12; ++kc) {
        const int k0 = kc * 64;
#pragma unroll
        for (int i = 0; i < 4; ++i) {
            const int c = tid + 256 * i;
            const int row = c >> 3, ko = (c & 7) * 8;
            *(uint4*)(As + row * 72 + ko) = *(const uint4*)(h + (size_t)(m0 + row) * 768 + k0 + ko);
        }
#pragma unroll
        for (int i = 0; i < 6; ++i) {
            const int c = tid + 256 * i;
            const int row = c >> 3, ko = (c & 7) * 8;
            *(uint4*)(Bs + row * 72 + ko) = *(const uint4*)(f2wT + (size_t)row * 768 + k0 + ko);
        }
        __syncthreads();
        const u16* pa = As + (wave * 32 + (lane & 15)) * 72 + (lane >> 4) * 8;
        const u16* pb = Bs + (lane & 15) * 72 + (lane >> 4) * 8;
#pragma unroll
        for (int ks = 0; ks < 2; ++ks) {
            const bf16x8 a0 = *(const bf16x8*)(pa + ks * 32);
            const bf16x8 a1 = *(const bf16x8*)(pa + 16 * 72 + ks * 32);
#pragma unroll
            for (int nj = 0; nj < 12; ++nj) {
                const bf16x8 b = *(const bf16x8*)(pb + nj * 16 * 72 + ks * 32);
                acc[0][nj] = __builtin_amdgcn_mfma_f32_16x16x32_bf16(a0, b, acc[0][nj], 0, 0, 0);
                acc[1][nj] = __builtin_amdgcn_mfma_f32_16x16x32_bf16(a1, b, acc[1][nj], 0, 0, 0);
            }
        }
        __syncthreads();
    }
#pragma unroll
    for (int nj = 0; nj < 12; ++nj) {
        const int n = nj * 16 + (lane & 15);
        const float bi = f2b[n];
#pragma unroll
        for (int mi = 0; mi < 2; ++mi)
#pragma unroll
            for (int r = 0; r < 4; ++r) {
                const int m = m0 + wave * 32 + mi * 16 + ((lane >> 4) << 2) + r;
                const size_t gi = (size_t)m * C_DIM + n;
                out[gi] = x2[gi] + bi + acc[0 + mi][nj][r];
            }
    }
}

// ---------------------------------------------------------------------------
// orchestration. ws (PB = 48MB): [0,PB) xw->o ; [PB,2PB) q ; [2PB,3PB) k ;
// [3PB,4PB) v ; h overlays [PB,5PB) after attn ; x2n [5PB,6PB) ; weights at 6PB.
// x2 = d_out fp32.
// ---------------------------------------------------------------------------
static void run_block(const float* X, float* XOUT,
                      const float* g1, const float* b1, const float* qb,
                      const float* rpb, const float* pb,
                      const float* g2, const float* b2,
                      const float* f1b, const float* f2b,
                      const u16* qwT, const u16* pwT, const u16* f1wT, const u16* f2wT,
                      int shifted, char* ws, hipStream_t stream) {
    const size_t PB = (size_t)L_TOK * C_DIM * sizeof(u16);  // 48 MB
    u16* xw  = (u16*)ws;
    u16* q   = (u16*)(ws + PB);
    u16* k   = (u16*)(ws + 2 * PB);
    u16* v   = (u16*)(ws + 3 * PB);
    u16* o   = xw;
    u16* h   = (u16*)(ws + PB);          // [PB,5PB): L x 768 bf16, overlays q,k,v
    u16* x2n = (u16*)(ws + 5 * PB);
    float* x2 = XOUT;

    ln_kernel<<<L_TOK / 4, 256, 0, stream>>>(X, g1, b1, xw, shifted ? 1 : 0);
    qkv_mfma<<<L_TOK / 128, 256, 0, stream>>>(xw, qwT, qb, q, k, v);
    attn_mfma<<<NWIN * 6, 256, 0, stream>>>(q, k, v, rpb, o, shifted);
    proj_ln_mfma<<<L_TOK / 128, 256, 0, stream>>>(o, pwT, pb, X, g2, b2, x2, x2n, shifted);
    fc1_mfma<<<L_TOK / 128, 256, 0, stream>>>(x2n, f1wT, f1b, h);
    fc2_mfma<<<L_TOK / 128, 256, 0, stream>>>(h, f2wT, f2b, x2, XOUT);
}

extern "C" void kernel_launch(void* const* d_in, const int* in_sizes, int n_in,
                              void* d_out, int out_size, void* d_ws, size_t ws_size,
                              hipStream_t stream) {
    const float* x = (const float*)d_in[0];
    float* out = (float*)d_out;
    char* ws = (char*)d_ws;
    auto in = [&](int i) { return (const float*)d_in[i]; };

    const size_t offW = (size_t)L_TOK * C_DIM * sizeof(u16) * 6;
    u16* wbase = (u16*)(ws + offW);
    const size_t SQ = 110592, SP = 36864, SF1 = 147456, SF2 = 147456;
    const size_t WBLK = SQ + SP + SF1 + SF2;
    u16* qwT[2]  = { wbase,                    wbase + WBLK };
    u16* pwT[2]  = { wbase + SQ,               wbase + WBLK + SQ };
    u16* f1wT[2] = { wbase + SQ + SP,          wbase + WBLK + SQ + SP };
    u16* f2wT[2] = { wbase + SQ + SP + SF1,    wbase + WBLK + SQ + SP + SF1 };

    wtrans_kernel<<<(192 * 576 + 255) / 256, 256, 0, stream>>>(in(3),  qwT[0],  192, 576);
    wtrans_kernel<<<(192 * 192 + 255) / 256, 256, 0, stream>>>(in(6),  pwT[0],  192, 192);
    wtrans_kernel<<<(192 * 768 + 255) / 256, 256, 0, stream>>>(in(10), f1wT[0], 192, 768);
    wtrans_kernel<<<(768 * 192 + 255) / 256, 256, 0, stream>>>(in(12), f2wT[0], 768, 192);
    wtrans_kernel<<<(192 * 576 + 255) / 256, 256, 0, stream>>>(in(16), qwT[1],  192, 576);
    wtrans_kernel<<<(192 * 192 + 255) / 256, 256, 0, stream>>>(in(19), pwT[1],  192, 192);
    wtrans_kernel<<<(192 * 768 + 255) / 256, 256, 0, stream>>>(in(23), f1wT[1], 192, 768);
    wtrans_kernel<<<(768 * 192 + 255) / 256, 256, 0, stream>>>(in(25), f2wT[1], 768, 192);

    run_block(x, out, in(1), in(2), in(4), in(5), in(7), in(8), in(9), in(11), in(13),
              qwT[0], pwT[0], f1wT[0], f2wT[0], 0, ws, stream);
    run_block(out, out, in(14), in(15), in(17), in(18), in(20), in(21), in(22), in(24), in(26),
              qwT[1], pwT[1], f1wT[1], f2wT[1], 1, ws, stream);
}

// Round 9
// 1131.693 us; speedup vs baseline: 1.5252x; 1.1772x over previous
//
#include <hip/hip_runtime.h>
#include <math.h>

// Swin-3D basic layer, bf16-MFMA: [LN1] [QKV] [attn] [proj+LN2] [FC1+gelu] [FC2+res]
// Round 9: swapped-operand GEMMs (A=weights, B=tokens) so each lane owns 4
// consecutive output channels of its own token row -> float4/ushort4 epilogues.
// proj nc-loop fully unrolled (fixes rule-#20 runtime-indexed acc -> scratch spill
// seen in r8: VGPR 152, WRITE 315MB, 206us).

#define L_TOK 131072
#define C_DIM 192
#define NWIN 2048

typedef unsigned int uint32;
typedef unsigned short u16;
typedef __bf16 bf16x8 __attribute__((ext_vector_type(8)));
typedef __bf16 bf16x4 __attribute__((ext_vector_type(4)));
typedef float f32x4 __attribute__((ext_vector_type(4)));

__device__ __forceinline__ u16 f2bf(float f) {
    uint32 u = __float_as_uint(f);
    u += 0x7fffu + ((u >> 16) & 1u);
    return (u16)(u >> 16);
}
__device__ __forceinline__ float bf2f(u16 h) { return __uint_as_float(((uint32)h) << 16); }

// exact-erf gelu via Abramowitz-Stegun 7.1.26 (|err| <= 1.5e-7)
__device__ __forceinline__ float gelu_f(float x) {
    const float ax = fabsf(x) * 0.7071067811865475f;
    const float t = 1.0f / fmaf(0.3275911f, ax, 1.0f);
    float poly = fmaf(1.061405429f, t, -1.453152027f);
    poly = fmaf(poly, t, 1.421413741f);
    poly = fmaf(poly, t, -0.284496736f);
    poly = fmaf(poly, t, 0.254829592f);
    poly *= t;
    float erfv = 1.0f - poly * __expf(-ax * ax);
    erfv = (x < 0.0f) ? -erfv : erfv;
    return 0.5f * x * (1.0f + erfv);
}

// window-ordered row r -> natural token index (rolled[g] = orig[(g+shift)%D])
__device__ __forceinline__ int win_row_to_token(int r, int shifted) {
    const int win = r >> 6, n = r & 63;
    const int sb = win >> 8, hb = (win >> 4) & 15, wb = win & 15;
    int gz = sb * 4 + (n >> 4);
    int gy = hb * 4 + ((n >> 2) & 3);
    int gx = wb * 4 + (n & 3);
    if (shifted) { gz = (gz + 2) & 31; gy = (gy + 2) & 63; gx = (gx + 2) & 63; }
    return (gz << 12) | (gy << 6) | gx;
}

// ---------------------------------------------------------------------------
// weight transpose + bf16 convert: in [K][N] fp32 -> out [N][K] bf16
// ---------------------------------------------------------------------------
__global__ __launch_bounds__(256) void wtrans_kernel(const float* __restrict__ in,
                                                     u16* __restrict__ out, int K, int N) {
    const int idx = blockIdx.x * 256 + threadIdx.x;
    if (idx < K * N) {
        const int n = idx / K, k = idx - n * K;
        out[idx] = f2bf(in[(size_t)k * N + n]);
    }
}

// ---------------------------------------------------------------------------
// LayerNorm (block entry): fp32 in -> bf16 out, window partition (+shift)
// ---------------------------------------------------------------------------
__global__ __launch_bounds__(256) void ln_kernel(const float* __restrict__ x,
                                                 const float* __restrict__ g,
                                                 const float* __restrict__ b,
                                                 u16* __restrict__ out, int mode) {
    const int r = blockIdx.x * 4 + (threadIdx.x >> 6);
    const int lane = threadIdx.x & 63;
    const int tin = win_row_to_token(r, mode);
    const float* xr = x + (size_t)tin * C_DIM;
    const float v0 = xr[lane], v1 = xr[lane + 64], v2 = xr[lane + 128];
    float s = v0 + v1 + v2;
#pragma unroll
    for (int off = 32; off >= 1; off >>= 1) s += __shfl_xor(s, off, 64);
    const float mu = s * (1.0f / 192.0f);
    const float d0 = v0 - mu, d1 = v1 - mu, d2 = v2 - mu;
    float sq = d0 * d0 + d1 * d1 + d2 * d2;
#pragma unroll
    for (int off = 32; off >= 1; off >>= 1) sq += __shfl_xor(sq, off, 64);
    const float rstd = rsqrtf(sq * (1.0f / 192.0f) + 1e-5f);
    u16* orow = out + (size_t)r * C_DIM;
    orow[lane]       = f2bf(d0 * rstd * g[lane]       + b[lane]);
    orow[lane + 64]  = f2bf(d1 * rstd * g[lane + 64]  + b[lane + 64]);
    orow[lane + 128] = f2bf(d2 * rstd * g[lane + 128] + b[lane + 128]);
}

// ---------------------------------------------------------------------------
// staging helpers for K=192 tiles (LDS row stride 200 u16)
// ---------------------------------------------------------------------------
__device__ __forceinline__ void stage_rows192(const u16* __restrict__ g, u16* __restrict__ s,
                                              int iters) {
    const int tid = threadIdx.x;
#pragma unroll
    for (int i = 0; i < iters; ++i) {
        const int c = tid + 256 * i;
        const int row = c / 24, ko = (c - row * 24) * 8;
        *(uint4*)(s + row * 200 + ko) = *(const uint4*)(g + (size_t)row * 192 + ko);
    }
}

// swapped-operand core: A = weight rows (Bs, 64 rows), B = token rows (As, this
// wave's 32). acc[a][tt]: channels 16a+4g+r (reg axis), token 16tt+i (lane axis).
__device__ __forceinline__ void compute192_swp(const u16* __restrict__ As,
                                               const u16* __restrict__ Bs,
                                               f32x4 (&acc)[4][2]) {
    const int lane = threadIdx.x & 63, wave = threadIdx.x >> 6;
    const int i = lane & 15, g = lane >> 4;
    const u16* pb = As + (wave * 32 + i) * 200 + 8 * g;   // token rows (B operand)
    const u16* pa = Bs + i * 200 + 8 * g;                 // weight rows (A operand)
#pragma unroll
    for (int ks = 0; ks < 6; ++ks) {
        const bf16x8 b0 = *(const bf16x8*)(pb + ks * 32);
        const bf16x8 b1 = *(const bf16x8*)(pb + 16 * 200 + ks * 32);
#pragma unroll
        for (int a = 0; a < 4; ++a) {
            const bf16x8 av = *(const bf16x8*)(pa + a * 16 * 200 + ks * 32);
            acc[a][0] = __builtin_amdgcn_mfma_f32_16x16x32_bf16(av, b0, acc[a][0], 0, 0, 0);
            acc[a][1] = __builtin_amdgcn_mfma_f32_16x16x32_bf16(av, b1, acc[a][1], 0, 0, 0);
        }
    }
}

// ---------------------------------------------------------------------------
// QKV: xw[M][192] @ qwT[576][192] -> q,k,v bf16 [win*6+head][64][32], q scaled.
// Swapped epilogue: lane owns 4 consecutive n for its token -> ushort4 stores.
// ---------------------------------------------------------------------------
__global__ __launch_bounds__(256) void qkv_mfma(const u16* __restrict__ xw,
                                                const u16* __restrict__ qwT,
                                                const float* __restrict__ qb,
                                                u16* __restrict__ q, u16* __restrict__ k,
                                                u16* __restrict__ v) {
    __shared__ __align__(16) u16 As[128 * 200];
    __shared__ __align__(16) u16 Bs[64 * 200];
    const int m0 = blockIdx.x * 128;
    const int lane = threadIdx.x & 63, wave = threadIdx.x >> 6;
    const int i = lane & 15, g = lane >> 4;
    stage_rows192(xw + (size_t)m0 * 192, As, 12);
#pragma unroll 1
    for (int nc = 0; nc < 9; ++nc) {
        stage_rows192(qwT + (size_t)nc * 64 * 192, Bs, 6);
        __syncthreads();
        f32x4 acc[4][2] = {};
        compute192_swp(As, Bs, acc);
        const int which = nc / 3;                       // chunk-uniform: 0..2->q,3..5->k,6..8->v
        u16* dst = (which == 0) ? q : (which == 1) ? k : v;
        const float sc = (which == 0) ? 0.17677669529663687f : 1.0f;
#pragma unroll
        for (int a = 0; a < 4; ++a) {
            const int n0 = nc * 64 + 16 * a + 4 * g;    // 4 consecutive n
            const int hn = n0 - which * 192;
            const int head = hn >> 5, hd0 = hn & 31;
            const float4 bi = *(const float4*)(qb + n0);
#pragma unroll
            for (int tt = 0; tt < 2; ++tt) {
                const int m = m0 + wave * 32 + 16 * tt + i;
                const int win = m >> 6, tok = m & 63;
                ushort4 pk;
                pk.x = f2bf((acc[a][tt][0] + bi.x) * sc);
                pk.y = f2bf((acc[a][tt][1] + bi.y) * sc);
                pk.z = f2bf((acc[a][tt][2] + bi.z) * sc);
                pk.w = f2bf((acc[a][tt][3] + bi.w) * sc);
                *(ushort4*)(dst + ((size_t)(win * 6 + head) * 64 + tok) * 32 + hd0) = pk;
            }
        }
        __syncthreads();
    }
}

// ---------------------------------------------------------------------------
// MFMA attention: one block per (win, head), 4 waves. Swapped QK^T. (unchanged)
// ---------------------------------------------------------------------------
__global__ __launch_bounds__(256) void attn_mfma(const u16* __restrict__ qg,
                                                 const u16* __restrict__ kg,
                                                 const u16* __restrict__ vg,
                                                 const float* __restrict__ rpb,
                                                 u16* __restrict__ o, int shifted) {
    __shared__ __align__(16) u16 vt[32 * 68];
    __shared__ __align__(16) u16 ps[64 * 68];
    __shared__ __align__(16) u16 os[64 * 40];
    __shared__ float bias_s[343];
    __shared__ int ms[64];
    const int tid = threadIdx.x;
    const int lane = tid & 63, w = tid >> 6;
    const int i = lane & 15, g = lane >> 4;
    const int head = blockIdx.x >> 11;
    const int win = blockIdx.x & 2047;
    const size_t base = (size_t)(win * 6 + head) * 2048;

    const bf16x8 qf = *(const bf16x8*)(qg + base + (size_t)(16 * w + i) * 32 + 8 * g);
    bf16x8 kf[4];
#pragma unroll
    for (int t = 0; t < 4; ++t)
        kf[t] = *(const bf16x8*)(kg + base + (size_t)(16 * t + i) * 32 + 8 * g);
    {
        const int n = tid >> 2, c0 = (tid & 3) * 8;
        uint4 raw = *(const uint4*)(vg + base + (size_t)n * 32 + c0);
        const u16* pr = (const u16*)&raw;
#pragma unroll
        for (int j = 0; j < 8; ++j) vt[(c0 + j) * 68 + n] = pr[j];
    }
    for (int idx = tid; idx < 343; idx += 256) bias_s[idx] = rpb[idx * 6 + head];
    if (tid < 64) {
        int mv = 0;
        if (shifted) {
            const int sb = win >> 8, hb = (win >> 4) & 15, wb = win & 15;
            const int gz = sb * 4 + (tid >> 4);
            const int gy = hb * 4 + ((tid >> 2) & 3);
            const int gx = wb * 4 + (tid & 3);
            const int rz = gz < 28 ? 0 : (gz < 30 ? 1 : 2);
            const int ry = gy < 60 ? 0 : (gy < 62 ? 1 : 2);
            const int rw = gx < 60 ? 0 : (gx < 62 ? 1 : 2);
            mv = rz * 9 + ry * 3 + rw;
        }
        ms[tid] = mv;
    }
    __syncthreads();

    const f32x4 zero = {0.0f, 0.0f, 0.0f, 0.0f};
    f32x4 s[4];
#pragma unroll
    for (int t = 0; t < 4; ++t)
        s[t] = __builtin_amdgcn_mfma_f32_16x16x32_bf16(kf[t], qf, zero, 0, 0, 0);

    const int qrow = 16 * w + i;
    const int mq = ms[qrow];
    float p[16];
#pragma unroll
    for (int t = 0; t < 4; ++t)
#pragma unroll
        for (int r = 0; r < 4; ++r) {
            const int j = 16 * t + 4 * g + r;
            const int dz = (qrow >> 4) - (j >> 4) + 3;
            const int dy = ((qrow >> 2) & 3) - ((j >> 2) & 3) + 3;
            const int dx = (qrow & 3) - (j & 3) + 3;
            float val = s[t][r] + bias_s[dz * 49 + dy * 7 + dx];
            if (shifted && (mq != ms[j])) val -= 100.0f;
            p[t * 4 + r] = val;
        }
    float mx = -3.0e38f;
#pragma unroll
    for (int u = 0; u < 16; ++u) mx = fmaxf(mx, p[u]);
    mx = fmaxf(mx, __shfl_xor(mx, 16, 64));
    mx = fmaxf(mx, __shfl_xor(mx, 32, 64));
    float sum = 0.0f;
#pragma unroll
    for (int u = 0; u < 16; ++u) { p[u] = __expf(p[u] - mx); sum += p[u]; }
    sum += __shfl_xor(sum, 16, 64);
    sum += __shfl_xor(sum, 32, 64);
    const float inv = 1.0f / sum;

#pragma unroll
    for (int t = 0; t < 4; ++t) {
        ushort4 pk;
        pk.x = f2bf(p[t * 4 + 0]); pk.y = f2bf(p[t * 4 + 1]);
        pk.z = f2bf(p[t * 4 + 2]); pk.w = f2bf(p[t * 4 + 3]);
        *(ushort4*)(ps + (size_t)qrow * 68 + 16 * t + 4 * g) = pk;
    }

    f32x4 oacc[2] = {zero, zero};
#pragma unroll
    for (int kb = 0; kb < 2; ++kb) {
        const bf16x4 alo = *(const bf16x4*)(ps + (size_t)qrow * 68 + 8 * g + 32 * kb);
        const bf16x4 ahi = *(const bf16x4*)(ps + (size_t)qrow * 68 + 8 * g + 32 * kb + 4);
        const bf16x8 a = __builtin_shufflevector(alo, ahi, 0, 1, 2, 3, 4, 5, 6, 7);
#pragma unroll
        for (int ct = 0; ct < 2; ++ct) {
            const bf16x4 blo = *(const bf16x4*)(vt + (size_t)(i + 16 * ct) * 68 + 8 * g + 32 * kb);
            const bf16x4 bhi = *(const bf16x4*)(vt + (size_t)(i + 16 * ct) * 68 + 8 * g + 32 * kb + 4);
            const bf16x8 b = __builtin_shufflevector(blo, bhi, 0, 1, 2, 3, 4, 5, 6, 7);
            oacc[ct] = __builtin_amdgcn_mfma_f32_16x16x32_bf16(a, b, oacc[ct], 0, 0, 0);
        }
    }
#pragma unroll
    for (int ct = 0; ct < 2; ++ct)
#pragma unroll
        for (int r = 0; r < 4; ++r) {
            const float ov = oacc[ct][r] * __shfl(inv, 4 * g + r, 64);
            os[(16 * w + 4 * g + r) * 40 + i + 16 * ct] = f2bf(ov);
        }
    __syncthreads();
    {
        const int n = tid >> 2, c0 = (tid & 3) * 8;
        const uint4 val = *(const uint4*)(os + n * 40 + c0);
        *(uint4*)(o + (size_t)(win * 64 + n) * C_DIM + head * 32 + c0) = val;
    }
}

// ---------------------------------------------------------------------------
// proj + residual + LN2 fused (swapped): lane owns channels {16a+4g..+3} of its
// token. acc[12][2] statically indexed (nc fully unrolled). LN reduce = 2 shfls
// across g-lanes. float4 x2 stores, ushort4 x2n stores, float4 xin reads.
// ---------------------------------------------------------------------------
__global__ __launch_bounds__(256) void proj_ln_mfma(const u16* __restrict__ o,
                                                    const u16* __restrict__ pwT,
                                                    const float* __restrict__ pb,
                                                    const float* xin,
                                                    const float* __restrict__ g2,
                                                    const float* __restrict__ b2,
                                                    float* x2, u16* __restrict__ x2n,
                                                    int shifted) {
    __shared__ __align__(16) u16 As[128 * 200];
    __shared__ __align__(16) u16 Bs[64 * 200];
    const int m0 = blockIdx.x * 128;
    const int lane = threadIdx.x & 63, wave = threadIdx.x >> 6;
    const int i = lane & 15, g = lane >> 4;
    stage_rows192(o + (size_t)m0 * 192, As, 12);
    f32x4 acc[12][2] = {};
#pragma unroll
    for (int nc = 0; nc < 3; ++nc) {                     // FULL unroll: static acc idx
        stage_rows192(pwT + (size_t)nc * 64 * 192, Bs, 6);
        __syncthreads();
        const u16* pbt = As + (wave * 32 + i) * 200 + 8 * g;
        const u16* paw = Bs + i * 200 + 8 * g;
#pragma unroll
        for (int ks = 0; ks < 6; ++ks) {
            const bf16x8 b0 = *(const bf16x8*)(pbt + ks * 32);
            const bf16x8 b1 = *(const bf16x8*)(pbt + 16 * 200 + ks * 32);
#pragma unroll
            for (int a = 0; a < 4; ++a) {
                const bf16x8 av = *(const bf16x8*)(paw + a * 16 * 200 + ks * 32);
                acc[nc * 4 + a][0] = __builtin_amdgcn_mfma_f32_16x16x32_bf16(av, b0, acc[nc * 4 + a][0], 0, 0, 0);
                acc[nc * 4 + a][1] = __builtin_amdgcn_mfma_f32_16x16x32_bf16(av, b1, acc[nc * 4 + a][1], 0, 0, 0);
            }
        }
        __syncthreads();
    }
#pragma unroll
    for (int tt = 0; tt < 2; ++tt) {
        const int m = m0 + wave * 32 + 16 * tt + i;
        const int t = win_row_to_token(m, shifted);
        const float* xr = xin + (size_t)t * C_DIM;
        float s = 0.0f;
#pragma unroll
        for (int a = 0; a < 12; ++a) {
            const int n0 = 16 * a + 4 * g;
            const float4 xv = *(const float4*)(xr + n0);
            const float4 bi = *(const float4*)(pb + n0);
            acc[a][tt][0] += xv.x + bi.x;
            acc[a][tt][1] += xv.y + bi.y;
            acc[a][tt][2] += xv.z + bi.z;
            acc[a][tt][3] += xv.w + bi.w;
            s += acc[a][tt][0] + acc[a][tt][1] + acc[a][tt][2] + acc[a][tt][3];
        }
        s += __shfl_xor(s, 16, 64);
        s += __shfl_xor(s, 32, 64);
        const float mu = s * (1.0f / 192.0f);
        float sq = 0.0f;
#pragma unroll
        for (int a = 0; a < 12; ++a) {
#pragma unroll
            for (int r = 0; r < 4; ++r) {
                const float d = acc[a][tt][r] - mu;
                sq += d * d;
            }
        }
        sq += __shfl_xor(sq, 16, 64);
        sq += __shfl_xor(sq, 32, 64);
        const float rstd = rsqrtf(sq * (1.0f / 192.0f) + 1e-5f);
        float* x2r = x2 + (size_t)t * C_DIM;
        u16* xnr = x2n + (size_t)t * C_DIM;
#pragma unroll
        for (int a = 0; a < 12; ++a) {
            const int n0 = 16 * a + 4 * g;
            float4 wv;
            wv.x = acc[a][tt][0]; wv.y = acc[a][tt][1];
            wv.z = acc[a][tt][2]; wv.w = acc[a][tt][3];
            *(float4*)(x2r + n0) = wv;
            const float4 gv = *(const float4*)(g2 + n0);
            const float4 bv = *(const float4*)(b2 + n0);
            ushort4 nk;
            nk.x = f2bf((wv.x - mu) * rstd * gv.x + bv.x);
            nk.y = f2bf((wv.y - mu) * rstd * gv.y + bv.y);
            nk.z = f2bf((wv.z - mu) * rstd * gv.z + bv.z);
            nk.w = f2bf((wv.w - mu) * rstd * gv.w + bv.w);
            *(ushort4*)(xnr + n0) = nk;
        }
    }
}

// ---------------------------------------------------------------------------
// FC1 + gelu (swapped): h = gelu(x2n @ f1w + f1b), ushort4 stores into h rows.
// ---------------------------------------------------------------------------
__global__ __launch_bounds__(256) void fc1_mfma(const u16* __restrict__ x2n,
                                                const u16* __restrict__ f1wT,
                                                const float* __restrict__ f1b,
                                                u16* __restrict__ h) {
    __shared__ __align__(16) u16 As[128 * 200];
    __shared__ __align__(16) u16 Bs[64 * 200];
    const int m0 = blockIdx.x * 128;
    const int lane = threadIdx.x & 63, wave = threadIdx.x >> 6;
    const int i = lane & 15, g = lane >> 4;
    stage_rows192(x2n + (size_t)m0 * 192, As, 12);
#pragma unroll 1
    for (int nc = 0; nc < 12; ++nc) {
        stage_rows192(f1wT + (size_t)nc * 64 * 192, Bs, 6);
        __syncthreads();
        f32x4 acc[4][2] = {};
        compute192_swp(As, Bs, acc);
#pragma unroll
        for (int a = 0; a < 4; ++a) {
            const int n0 = nc * 64 + 16 * a + 4 * g;
            const float4 bi = *(const float4*)(f1b + n0);
#pragma unroll
            for (int tt = 0; tt < 2; ++tt) {
                const int m = m0 + wave * 32 + 16 * tt + i;
                ushort4 pk;
                pk.x = f2bf(gelu_f(acc[a][tt][0] + bi.x));
                pk.y = f2bf(gelu_f(acc[a][tt][1] + bi.y));
                pk.z = f2bf(gelu_f(acc[a][tt][2] + bi.z));
                pk.w = f2bf(gelu_f(acc[a][tt][3] + bi.w));
                *(ushort4*)(h + (size_t)m * 768 + n0) = pk;
            }
        }
        __syncthreads();
    }
}

// ---------------------------------------------------------------------------
// FC2 + residual (swapped): out = x2 + h @ f2w + f2b (out may alias x2).
// K-loop BK=64; acc[12][2] static; float4 residual reads + float4 stores.
// ---------------------------------------------------------------------------
__global__ __launch_bounds__(256) void fc2_mfma(const u16* __restrict__ h,
                                                const u16* __restrict__ f2wT,
                                                const float* __restrict__ f2b,
                                                const float* x2, float* out) {
    __shared__ __align__(16) u16 As[128 * 72];
    __shared__ __align__(16) u16 Bs[192 * 72];
    const int tid = threadIdx.x, lane = tid & 63, wave = tid >> 6;
    const int i = lane & 15, g = lane >> 4;
    const int m0 = blockIdx.x * 128;
    f32x4 acc[12][2] = {};
#pragma unroll 1
    for (int kc = 0; kc < 12; ++kc) {
        const int k0 = kc * 64;
#pragma unroll
        for (int u = 0; u < 4; ++u) {
            const int c = tid + 256 * u;
            const int row = c >> 3, ko = (c & 7) * 8;
            *(uint4*)(As + row * 72 + ko) = *(const uint4*)(h + (size_t)(m0 + row) * 768 + k0 + ko);
        }
#pragma unroll
        for (int u = 0; u < 6; ++u) {
            const int c = tid + 256 * u;
            const int row = c >> 3, ko = (c & 7) * 8;
            *(uint4*)(Bs + row * 72 + ko) = *(const uint4*)(f2wT + (size_t)row * 768 + k0 + ko);
        }
        __syncthreads();
        const u16* pbt = As + (wave * 32 + i) * 72 + 8 * g;   // token rows (B)
        const u16* paw = Bs + i * 72 + 8 * g;                 // channel rows (A)
#pragma unroll
        for (int ks = 0; ks < 2; ++ks) {
            const bf16x8 b0 = *(const bf16x8*)(pbt + ks * 32);
            const bf16x8 b1 = *(const bf16x8*)(pbt + 16 * 72 + ks * 32);
#pragma unroll
            for (int a = 0; a < 12; ++a) {
                const bf16x8 av = *(const bf16x8*)(paw + a * 16 * 72 + ks * 32);
                acc[a][0] = __builtin_amdgcn_mfma_f32_16x16x32_bf16(av, b0, acc[a][0], 0, 0, 0);
                acc[a][1] = __builtin_amdgcn_mfma_f32_16x16x32_bf16(av, b1, acc[a][1], 0, 0, 0);
            }
        }
        __syncthreads();
    }
#pragma unroll
    for (int tt = 0; tt < 2; ++tt) {
        const int m = m0 + wave * 32 + 16 * tt + i;
        const float* x2r = x2 + (size_t)m * C_DIM;
        float* orow = out + (size_t)m * C_DIM;
#pragma unroll
        for (int a = 0; a < 12; ++a) {
            const int n0 = 16 * a + 4 * g;
            const float4 xv = *(const float4*)(x2r + n0);
            const float4 bi = *(const float4*)(f2b + n0);
            float4 rr;
            rr.x = xv.x + bi.x + acc[a][tt][0];
            rr.y = xv.y + bi.y + acc[a][tt][1];
            rr.z = xv.z + bi.z + acc[a][tt][2];
            rr.w = xv.w + bi.w + acc[a][tt][3];
            *(float4*)(orow + n0) = rr;
        }
    }
}

// ---------------------------------------------------------------------------
// orchestration. ws (PB = 48MB): [0,PB) xw->o ; [PB,2PB) q ; [2PB,3PB) k ;
// [3PB,4PB) v ; h overlays [PB,5PB) after attn ; x2n [5PB,6PB) ; weights at 6PB.
// x2 = d_out fp32.
// ---------------------------------------------------------------------------
static void run_block(const float* X, float* XOUT,
                      const float* g1, const float* b1, const float* qb,
                      const float* rpb, const float* pb,
                      const float* g2, const float* b2,
                      const float* f1b, const float* f2b,
                      const u16* qwT, const u16* pwT, const u16* f1wT, const u16* f2wT,
                      int shifted, char* ws, hipStream_t stream) {
    const size_t PB = (size_t)L_TOK * C_DIM * sizeof(u16);  // 48 MB
    u16* xw  = (u16*)ws;
    u16* q   = (u16*)(ws + PB);
    u16* k   = (u16*)(ws + 2 * PB);
    u16* v   = (u16*)(ws + 3 * PB);
    u16* o   = xw;
    u16* h   = (u16*)(ws + PB);          // [PB,5PB): L x 768 bf16, overlays q,k,v
    u16* x2n = (u16*)(ws + 5 * PB);
    float* x2 = XOUT;

    ln_kernel<<<L_TOK / 4, 256, 0, stream>>>(X, g1, b1, xw, shifted ? 1 : 0);
    qkv_mfma<<<L_TOK / 128, 256, 0, stream>>>(xw, qwT, qb, q, k, v);
    attn_mfma<<<NWIN * 6, 256, 0, stream>>>(q, k, v, rpb, o, shifted);
    proj_ln_mfma<<<L_TOK / 128, 256, 0, stream>>>(o, pwT, pb, X, g2, b2, x2, x2n, shifted);
    fc1_mfma<<<L_TOK / 128, 256, 0, stream>>>(x2n, f1wT, f1b, h);
    fc2_mfma<<<L_TOK / 128, 256, 0, stream>>>(h, f2wT, f2b, x2, XOUT);
}

extern "C" void kernel_launch(void* const* d_in, const int* in_sizes, int n_in,
                              void* d_out, int out_size, void* d_ws, size_t ws_size,
                              hipStream_t stream) {
    const float* x = (const float*)d_in[0];
    float* out = (float*)d_out;
    char* ws = (char*)d_ws;
    auto in = [&](int i) { return (const float*)d_in[i]; };

    const size_t offW = (size_t)L_TOK * C_DIM * sizeof(u16) * 6;
    u16* wbase = (u16*)(ws + offW);
    const size_t SQ = 110592, SP = 36864, SF1 = 147456, SF2 = 147456;
    const size_t WBLK = SQ + SP + SF1 + SF2;
    u16* qwT[2]  = { wbase,                    wbase + WBLK };
    u16* pwT[2]  = { wbase + SQ,               wbase + WBLK + SQ };
    u16* f1wT[2] = { wbase + SQ + SP,          wbase + WBLK + SQ + SP };
    u16* f2wT[2] = { wbase + SQ + SP + SF1,    wbase + WBLK + SQ + SP + SF1 };

    wtrans_kernel<<<(192 * 576 + 255) / 256, 256, 0, stream>>>(in(3),  qwT[0],  192, 576);
    wtrans_kernel<<<(192 * 192 + 255) / 256, 256, 0, stream>>>(in(6),  pwT[0],  192, 192);
    wtrans_kernel<<<(192 * 768 + 255) / 256, 256, 0, stream>>>(in(10), f1wT[0], 192, 768);
    wtrans_kernel<<<(768 * 192 + 255) / 256, 256, 0, stream>>>(in(12), f2wT[0], 768, 192);
    wtrans_kernel<<<(192 * 576 + 255) / 256, 256, 0, stream>>>(in(16), qwT[1],  192, 576);
    wtrans_kernel<<<(192 * 192 + 255) / 256, 256, 0, stream>>>(in(19), pwT[1],  192, 192);
    wtrans_kernel<<<(192 * 768 + 255) / 256, 256, 0, stream>>>(in(23), f1wT[1], 192, 768);
    wtrans_kernel<<<(768 * 192 + 255) / 256, 256, 0, stream>>>(in(25), f2wT[1], 768, 192);

    run_block(x, out, in(1), in(2), in(4), in(5), in(7), in(8), in(9), in(11), in(13),
              qwT[0], pwT[0], f1wT[0], f2wT[0], 0, ws, stream);
    run_block(out, out, in(14), in(15), in(17), in(18), in(20), in(21), in(22), in(24), in(26),
              qwT[1], pwT[1], f1wT[1], f2wT[1], 1, ws, stream);
}

// Round 10
// 997.818 us; speedup vs baseline: 1.7298x; 1.1342x over previous
//
#include <hip/hip_runtime.h>
#include <math.h>

// Swin-3D basic layer, bf16-MFMA: [LN1] [QKV] [attn] [proj+LN2] [FC1+gelu] [FC2+res]
// Round 10: qkv/fc1 restructured — wave-private token rows in REGISTERS (B operand),
// double-buffered weight LDS tile, ONE barrier per chunk. LDS 76.8->51.2KB (3 blk/CU).

#define L_TOK 131072
#define C_DIM 192
#define NWIN 2048

typedef unsigned int uint32;
typedef unsigned short u16;
typedef __bf16 bf16x8 __attribute__((ext_vector_type(8)));
typedef __bf16 bf16x4 __attribute__((ext_vector_type(4)));
typedef float f32x4 __attribute__((ext_vector_type(4)));

__device__ __forceinline__ u16 f2bf(float f) {
    uint32 u = __float_as_uint(f);
    u += 0x7fffu + ((u >> 16) & 1u);
    return (u16)(u >> 16);
}
__device__ __forceinline__ float bf2f(u16 h) { return __uint_as_float(((uint32)h) << 16); }

// exact-erf gelu via Abramowitz-Stegun 7.1.26 (|err| <= 1.5e-7)
__device__ __forceinline__ float gelu_f(float x) {
    const float ax = fabsf(x) * 0.7071067811865475f;
    const float t = 1.0f / fmaf(0.3275911f, ax, 1.0f);
    float poly = fmaf(1.061405429f, t, -1.453152027f);
    poly = fmaf(poly, t, 1.421413741f);
    poly = fmaf(poly, t, -0.284496736f);
    poly = fmaf(poly, t, 0.254829592f);
    poly *= t;
    float erfv = 1.0f - poly * __expf(-ax * ax);
    erfv = (x < 0.0f) ? -erfv : erfv;
    return 0.5f * x * (1.0f + erfv);
}

// window-ordered row r -> natural token index (rolled[g] = orig[(g+shift)%D])
__device__ __forceinline__ int win_row_to_token(int r, int shifted) {
    const int win = r >> 6, n = r & 63;
    const int sb = win >> 8, hb = (win >> 4) & 15, wb = win & 15;
    int gz = sb * 4 + (n >> 4);
    int gy = hb * 4 + ((n >> 2) & 3);
    int gx = wb * 4 + (n & 3);
    if (shifted) { gz = (gz + 2) & 31; gy = (gy + 2) & 63; gx = (gx + 2) & 63; }
    return (gz << 12) | (gy << 6) | gx;
}

// ---------------------------------------------------------------------------
// weight transpose + bf16 convert: in [K][N] fp32 -> out [N][K] bf16
// ---------------------------------------------------------------------------
__global__ __launch_bounds__(256) void wtrans_kernel(const float* __restrict__ in,
                                                     u16* __restrict__ out, int K, int N) {
    const int idx = blockIdx.x * 256 + threadIdx.x;
    if (idx < K * N) {
        const int n = idx / K, k = idx - n * K;
        out[idx] = f2bf(in[(size_t)k * N + n]);
    }
}

// ---------------------------------------------------------------------------
// LayerNorm (block entry): fp32 in -> bf16 out, window partition (+shift)
// ---------------------------------------------------------------------------
__global__ __launch_bounds__(256) void ln_kernel(const float* __restrict__ x,
                                                 const float* __restrict__ g,
                                                 const float* __restrict__ b,
                                                 u16* __restrict__ out, int mode) {
    const int r = blockIdx.x * 4 + (threadIdx.x >> 6);
    const int lane = threadIdx.x & 63;
    const int tin = win_row_to_token(r, mode);
    const float* xr = x + (size_t)tin * C_DIM;
    const float v0 = xr[lane], v1 = xr[lane + 64], v2 = xr[lane + 128];
    float s = v0 + v1 + v2;
#pragma unroll
    for (int off = 32; off >= 1; off >>= 1) s += __shfl_xor(s, off, 64);
    const float mu = s * (1.0f / 192.0f);
    const float d0 = v0 - mu, d1 = v1 - mu, d2 = v2 - mu;
    float sq = d0 * d0 + d1 * d1 + d2 * d2;
#pragma unroll
    for (int off = 32; off >= 1; off >>= 1) sq += __shfl_xor(sq, off, 64);
    const float rstd = rsqrtf(sq * (1.0f / 192.0f) + 1e-5f);
    u16* orow = out + (size_t)r * C_DIM;
    orow[lane]       = f2bf(d0 * rstd * g[lane]       + b[lane]);
    orow[lane + 64]  = f2bf(d1 * rstd * g[lane + 64]  + b[lane + 64]);
    orow[lane + 128] = f2bf(d2 * rstd * g[lane + 128] + b[lane + 128]);
}

// ---------------------------------------------------------------------------
// staging helpers (LDS row stride 200 u16)
// ---------------------------------------------------------------------------
__device__ __forceinline__ void stage_rows192(const u16* __restrict__ g, u16* __restrict__ s,
                                              int iters) {
    const int tid = threadIdx.x;
#pragma unroll
    for (int i = 0; i < iters; ++i) {
        const int c = tid + 256 * i;
        const int row = c / 24, ko = (c - row * 24) * 8;
        *(uint4*)(s + row * 200 + ko) = *(const uint4*)(g + (size_t)row * 192 + ko);
    }
}

// load this wave's 32 token rows (K=192) into B-operand register fragments
__device__ __forceinline__ void load_tok_regs(const u16* __restrict__ base, bf16x8 (&xb)[2][6]) {
    const int lane = threadIdx.x & 63, wave = threadIdx.x >> 6;
    const int i = lane & 15, g = lane >> 4;
#pragma unroll
    for (int tt = 0; tt < 2; ++tt)
#pragma unroll
        for (int ks = 0; ks < 6; ++ks)
            xb[tt][ks] = *(const bf16x8*)(base + (size_t)(32 * wave + 16 * tt + i) * 192 +
                                          32 * ks + 8 * g);
}

// ---------------------------------------------------------------------------
// QKV (A=weights/B=token-regs, dbuf weights, 1 barrier/chunk):
// xw[M][192] @ qwT[576][192] -> q,k,v bf16 [win*6+head][64][32], q scaled.
// ---------------------------------------------------------------------------
__global__ __launch_bounds__(256) void qkv_mfma(const u16* __restrict__ xw,
                                                const u16* __restrict__ qwT,
                                                const float* __restrict__ qb,
                                                u16* __restrict__ q, u16* __restrict__ k,
                                                u16* __restrict__ v) {
    __shared__ __align__(16) u16 Bs[2][64 * 200];
    const int m0 = blockIdx.x * 128;
    const int lane = threadIdx.x & 63, wave = threadIdx.x >> 6;
    const int i = lane & 15, g = lane >> 4;
    bf16x8 xb[2][6];
    load_tok_regs(xw + (size_t)m0 * 192, xb);
    stage_rows192(qwT, Bs[0], 6);
    __syncthreads();
#pragma unroll 1
    for (int nc = 0; nc < 9; ++nc) {
        const int cur = nc & 1;
        if (nc < 8) stage_rows192(qwT + (size_t)(nc + 1) * 64 * 192, Bs[cur ^ 1], 6);
        f32x4 acc[4][2] = {};
        const u16* paw = Bs[cur] + i * 200 + 8 * g;
#pragma unroll
        for (int ks = 0; ks < 6; ++ks) {
#pragma unroll
            for (int a = 0; a < 4; ++a) {
                const bf16x8 av = *(const bf16x8*)(paw + a * 16 * 200 + ks * 32);
                acc[a][0] = __builtin_amdgcn_mfma_f32_16x16x32_bf16(av, xb[0][ks], acc[a][0], 0, 0, 0);
                acc[a][1] = __builtin_amdgcn_mfma_f32_16x16x32_bf16(av, xb[1][ks], acc[a][1], 0, 0, 0);
            }
        }
        const int which = nc / 3;
        u16* dst = (which == 0) ? q : (which == 1) ? k : v;
        const float sc = (which == 0) ? 0.17677669529663687f : 1.0f;
#pragma unroll
        for (int a = 0; a < 4; ++a) {
            const int n0 = nc * 64 + 16 * a + 4 * g;
            const int hn = n0 - which * 192;
            const int head = hn >> 5, hd0 = hn & 31;
            const float4 bi = *(const float4*)(qb + n0);
#pragma unroll
            for (int tt = 0; tt < 2; ++tt) {
                const int m = m0 + wave * 32 + 16 * tt + i;
                const int win = m >> 6, tok = m & 63;
                ushort4 pk;
                pk.x = f2bf((acc[a][tt][0] + bi.x) * sc);
                pk.y = f2bf((acc[a][tt][1] + bi.y) * sc);
                pk.z = f2bf((acc[a][tt][2] + bi.z) * sc);
                pk.w = f2bf((acc[a][tt][3] + bi.w) * sc);
                *(ushort4*)(dst + ((size_t)(win * 6 + head) * 64 + tok) * 32 + hd0) = pk;
            }
        }
        __syncthreads();
    }
}

// ---------------------------------------------------------------------------
// MFMA attention: one block per (win, head), 4 waves. Swapped QK^T. (unchanged)
// ---------------------------------------------------------------------------
__global__ __launch_bounds__(256) void attn_mfma(const u16* __restrict__ qg,
                                                 const u16* __restrict__ kg,
                                                 const u16* __restrict__ vg,
                                                 const float* __restrict__ rpb,
                                                 u16* __restrict__ o, int shifted) {
    __shared__ __align__(16) u16 vt[32 * 68];
    __shared__ __align__(16) u16 ps[64 * 68];
    __shared__ __align__(16) u16 os[64 * 40];
    __shared__ float bias_s[343];
    __shared__ int ms[64];
    const int tid = threadIdx.x;
    const int lane = tid & 63, w = tid >> 6;
    const int i = lane & 15, g = lane >> 4;
    const int head = blockIdx.x >> 11;
    const int win = blockIdx.x & 2047;
    const size_t base = (size_t)(win * 6 + head) * 2048;

    const bf16x8 qf = *(const bf16x8*)(qg + base + (size_t)(16 * w + i) * 32 + 8 * g);
    bf16x8 kf[4];
#pragma unroll
    for (int t = 0; t < 4; ++t)
        kf[t] = *(const bf16x8*)(kg + base + (size_t)(16 * t + i) * 32 + 8 * g);
    {
        const int n = tid >> 2, c0 = (tid & 3) * 8;
        uint4 raw = *(const uint4*)(vg + base + (size_t)n * 32 + c0);
        const u16* pr = (const u16*)&raw;
#pragma unroll
        for (int j = 0; j < 8; ++j) vt[(c0 + j) * 68 + n] = pr[j];
    }
    for (int idx = tid; idx < 343; idx += 256) bias_s[idx] = rpb[idx * 6 + head];
    if (tid < 64) {
        int mv = 0;
        if (shifted) {
            const int sb = win >> 8, hb = (win >> 4) & 15, wb = win & 15;
            const int gz = sb * 4 + (tid >> 4);
            const int gy = hb * 4 + ((tid >> 2) & 3);
            const int gx = wb * 4 + (tid & 3);
            const int rz = gz < 28 ? 0 : (gz < 30 ? 1 : 2);
            const int ry = gy < 60 ? 0 : (gy < 62 ? 1 : 2);
            const int rw = gx < 60 ? 0 : (gx < 62 ? 1 : 2);
            mv = rz * 9 + ry * 3 + rw;
        }
        ms[tid] = mv;
    }
    __syncthreads();

    const f32x4 zero = {0.0f, 0.0f, 0.0f, 0.0f};
    f32x4 s[4];
#pragma unroll
    for (int t = 0; t < 4; ++t)
        s[t] = __builtin_amdgcn_mfma_f32_16x16x32_bf16(kf[t], qf, zero, 0, 0, 0);

    const int qrow = 16 * w + i;
    const int mq = ms[qrow];
    float p[16];
#pragma unroll
    for (int t = 0; t < 4; ++t)
#pragma unroll
        for (int r = 0; r < 4; ++r) {
            const int j = 16 * t + 4 * g + r;
            const int dz = (qrow >> 4) - (j >> 4) + 3;
            const int dy = ((qrow >> 2) & 3) - ((j >> 2) & 3) + 3;
            const int dx = (qrow & 3) - (j & 3) + 3;
            float val = s[t][r] + bias_s[dz * 49 + dy * 7 + dx];
            if (shifted && (mq != ms[j])) val -= 100.0f;
            p[t * 4 + r] = val;
        }
    float mx = -3.0e38f;
#pragma unroll
    for (int u = 0; u < 16; ++u) mx = fmaxf(mx, p[u]);
    mx = fmaxf(mx, __shfl_xor(mx, 16, 64));
    mx = fmaxf(mx, __shfl_xor(mx, 32, 64));
    float sum = 0.0f;
#pragma unroll
    for (int u = 0; u < 16; ++u) { p[u] = __expf(p[u] - mx); sum += p[u]; }
    sum += __shfl_xor(sum, 16, 64);
    sum += __shfl_xor(sum, 32, 64);
    const float inv = 1.0f / sum;

#pragma unroll
    for (int t = 0; t < 4; ++t) {
        ushort4 pk;
        pk.x = f2bf(p[t * 4 + 0]); pk.y = f2bf(p[t * 4 + 1]);
        pk.z = f2bf(p[t * 4 + 2]); pk.w = f2bf(p[t * 4 + 3]);
        *(ushort4*)(ps + (size_t)qrow * 68 + 16 * t + 4 * g) = pk;
    }

    f32x4 oacc[2] = {zero, zero};
#pragma unroll
    for (int kb = 0; kb < 2; ++kb) {
        const bf16x4 alo = *(const bf16x4*)(ps + (size_t)qrow * 68 + 8 * g + 32 * kb);
        const bf16x4 ahi = *(const bf16x4*)(ps + (size_t)qrow * 68 + 8 * g + 32 * kb + 4);
        const bf16x8 a = __builtin_shufflevector(alo, ahi, 0, 1, 2, 3, 4, 5, 6, 7);
#pragma unroll
        for (int ct = 0; ct < 2; ++ct) {
            const bf16x4 blo = *(const bf16x4*)(vt + (size_t)(i + 16 * ct) * 68 + 8 * g + 32 * kb);
            const bf16x4 bhi = *(const bf16x4*)(vt + (size_t)(i + 16 * ct) * 68 + 8 * g + 32 * kb + 4);
            const bf16x8 b = __builtin_shufflevector(blo, bhi, 0, 1, 2, 3, 4, 5, 6, 7);
            oacc[ct] = __builtin_amdgcn_mfma_f32_16x16x32_bf16(a, b, oacc[ct], 0, 0, 0);
        }
    }
#pragma unroll
    for (int ct = 0; ct < 2; ++ct)
#pragma unroll
        for (int r = 0; r < 4; ++r) {
            const float ov = oacc[ct][r] * __shfl(inv, 4 * g + r, 64);
            os[(16 * w + 4 * g + r) * 40 + i + 16 * ct] = f2bf(ov);
        }
    __syncthreads();
    {
        const int n = tid >> 2, c0 = (tid & 3) * 8;
        const uint4 val = *(const uint4*)(os + n * 40 + c0);
        *(uint4*)(o + (size_t)(win * 64 + n) * C_DIM + head * 32 + c0) = val;
    }
}

// ---------------------------------------------------------------------------
// proj + residual + LN2 fused (swapped, unchanged from r9)
// ---------------------------------------------------------------------------
__global__ __launch_bounds__(256) void proj_ln_mfma(const u16* __restrict__ o,
                                                    const u16* __restrict__ pwT,
                                                    const float* __restrict__ pb,
                                                    const float* xin,
                                                    const float* __restrict__ g2,
                                                    const float* __restrict__ b2,
                                                    float* x2, u16* __restrict__ x2n,
                                                    int shifted) {
    __shared__ __align__(16) u16 As[128 * 200];
    __shared__ __align__(16) u16 Bs[64 * 200];
    const int m0 = blockIdx.x * 128;
    const int lane = threadIdx.x & 63, wave = threadIdx.x >> 6;
    const int i = lane & 15, g = lane >> 4;
    stage_rows192(o + (size_t)m0 * 192, As, 12);
    f32x4 acc[12][2] = {};
#pragma unroll
    for (int nc = 0; nc < 3; ++nc) {
        stage_rows192(pwT + (size_t)nc * 64 * 192, Bs, 6);
        __syncthreads();
        const u16* pbt = As + (wave * 32 + i) * 200 + 8 * g;
        const u16* paw = Bs + i * 200 + 8 * g;
#pragma unroll
        for (int ks = 0; ks < 6; ++ks) {
            const bf16x8 b0 = *(const bf16x8*)(pbt + ks * 32);
            const bf16x8 b1 = *(const bf16x8*)(pbt + 16 * 200 + ks * 32);
#pragma unroll
            for (int a = 0; a < 4; ++a) {
                const bf16x8 av = *(const bf16x8*)(paw + a * 16 * 200 + ks * 32);
                acc[nc * 4 + a][0] = __builtin_amdgcn_mfma_f32_16x16x32_bf16(av, b0, acc[nc * 4 + a][0], 0, 0, 0);
                acc[nc * 4 + a][1] = __builtin_amdgcn_mfma_f32_16x16x32_bf16(av, b1, acc[nc * 4 + a][1], 0, 0, 0);
            }
        }
        __syncthreads();
    }
#pragma unroll
    for (int tt = 0; tt < 2; ++tt) {
        const int m = m0 + wave * 32 + 16 * tt + i;
        const int t = win_row_to_token(m, shifted);
        const float* xr = xin + (size_t)t * C_DIM;
        float s = 0.0f;
#pragma unroll
        for (int a = 0; a < 12; ++a) {
            const int n0 = 16 * a + 4 * g;
            const float4 xv = *(const float4*)(xr + n0);
            const float4 bi = *(const float4*)(pb + n0);
            acc[a][tt][0] += xv.x + bi.x;
            acc[a][tt][1] += xv.y + bi.y;
            acc[a][tt][2] += xv.z + bi.z;
            acc[a][tt][3] += xv.w + bi.w;
            s += acc[a][tt][0] + acc[a][tt][1] + acc[a][tt][2] + acc[a][tt][3];
        }
        s += __shfl_xor(s, 16, 64);
        s += __shfl_xor(s, 32, 64);
        const float mu = s * (1.0f / 192.0f);
        float sq = 0.0f;
#pragma unroll
        for (int a = 0; a < 12; ++a) {
#pragma unroll
            for (int r = 0; r < 4; ++r) {
                const float d = acc[a][tt][r] - mu;
                sq += d * d;
            }
        }
        sq += __shfl_xor(sq, 16, 64);
        sq += __shfl_xor(sq, 32, 64);
        const float rstd = rsqrtf(sq * (1.0f / 192.0f) + 1e-5f);
        float* x2r = x2 + (size_t)t * C_DIM;
        u16* xnr = x2n + (size_t)t * C_DIM;
#pragma unroll
        for (int a = 0; a < 12; ++a) {
            const int n0 = 16 * a + 4 * g;
            float4 wv;
            wv.x = acc[a][tt][0]; wv.y = acc[a][tt][1];
            wv.z = acc[a][tt][2]; wv.w = acc[a][tt][3];
            *(float4*)(x2r + n0) = wv;
            const float4 gv = *(const float4*)(g2 + n0);
            const float4 bv = *(const float4*)(b2 + n0);
            ushort4 nk;
            nk.x = f2bf((wv.x - mu) * rstd * gv.x + bv.x);
            nk.y = f2bf((wv.y - mu) * rstd * gv.y + bv.y);
            nk.z = f2bf((wv.z - mu) * rstd * gv.z + bv.z);
            nk.w = f2bf((wv.w - mu) * rstd * gv.w + bv.w);
            *(ushort4*)(xnr + n0) = nk;
        }
    }
}

// ---------------------------------------------------------------------------
// FC1 + gelu (A=weights/B=token-regs, dbuf weights, 1 barrier/chunk):
// h = gelu(x2n @ f1w + f1b), ushort4 stores into h rows.
// ---------------------------------------------------------------------------
__global__ __launch_bounds__(256) void fc1_mfma(const u16* __restrict__ x2n,
                                                const u16* __restrict__ f1wT,
                                                const float* __restrict__ f1b,
                                                u16* __restrict__ h) {
    __shared__ __align__(16) u16 Bs[2][64 * 200];
    const int m0 = blockIdx.x * 128;
    const int lane = threadIdx.x & 63, wave = threadIdx.x >> 6;
    const int i = lane & 15, g = lane >> 4;
    bf16x8 xb[2][6];
    load_tok_regs(x2n + (size_t)m0 * 192, xb);
    stage_rows192(f1wT, Bs[0], 6);
    __syncthreads();
#pragma unroll 1
    for (int nc = 0; nc < 12; ++nc) {
        const int cur = nc & 1;
        if (nc < 11) stage_rows192(f1wT + (size_t)(nc + 1) * 64 * 192, Bs[cur ^ 1], 6);
        f32x4 acc[4][2] = {};
        const u16* paw = Bs[cur] + i * 200 + 8 * g;
#pragma unroll
        for (int ks = 0; ks < 6; ++ks) {
#pragma unroll
            for (int a = 0; a < 4; ++a) {
                const bf16x8 av = *(const bf16x8*)(paw + a * 16 * 200 + ks * 32);
                acc[a][0] = __builtin_amdgcn_mfma_f32_16x16x32_bf16(av, xb[0][ks], acc[a][0], 0, 0, 0);
                acc[a][1] = __builtin_amdgcn_mfma_f32_16x16x32_bf16(av, xb[1][ks], acc[a][1], 0, 0, 0);
            }
        }
#pragma unroll
        for (int a = 0; a < 4; ++a) {
            const int n0 = nc * 64 + 16 * a + 4 * g;
            const float4 bi = *(const float4*)(f1b + n0);
#pragma unroll
            for (int tt = 0; tt < 2; ++tt) {
                const int m = m0 + wave * 32 + 16 * tt + i;
                ushort4 pk;
                pk.x = f2bf(gelu_f(acc[a][tt][0] + bi.x));
                pk.y = f2bf(gelu_f(acc[a][tt][1] + bi.y));
                pk.z = f2bf(gelu_f(acc[a][tt][2] + bi.z));
                pk.w = f2bf(gelu_f(acc[a][tt][3] + bi.w));
                *(ushort4*)(h + (size_t)m * 768 + n0) = pk;
            }
        }
        __syncthreads();
    }
}

// ---------------------------------------------------------------------------
// FC2 + residual (swapped, unchanged from r9): out = x2 + h @ f2w + f2b.
// ---------------------------------------------------------------------------
__global__ __launch_bounds__(256) void fc2_mfma(const u16* __restrict__ h,
                                                const u16* __restrict__ f2wT,
                                                const float* __restrict__ f2b,
                                                const float* x2, float* out) {
    __shared__ __align__(16) u16 As[128 * 72];
    __shared__ __align__(16) u16 Bs[192 * 72];
    const int tid = threadIdx.x, lane = tid & 63, wave = tid >> 6;
    const int i = lane & 15, g = lane >> 4;
    const int m0 = blockIdx.x * 128;
    f32x4 acc[12][2] = {};
#pragma unroll 1
    for (int kc = 0; kc < 12; ++kc) {
        const int k0 = kc * 64;
#pragma unroll
        for (int u = 0; u < 4; ++u) {
            const int c = tid + 256 * u;
            const int row = c >> 3, ko = (c & 7) * 8;
            *(uint4*)(As + row * 72 + ko) = *(const uint4*)(h + (size_t)(m0 + row) * 768 + k0 + ko);
        }
#pragma unroll
        for (int u = 0; u < 6; ++u) {
            const int c = tid + 256 * u;
            const int row = c >> 3, ko = (c & 7) * 8;
            *(uint4*)(Bs + row * 72 + ko) = *(const uint4*)(f2wT + (size_t)row * 768 + k0 + ko);
        }
        __syncthreads();
        const u16* pbt = As + (wave * 32 + i) * 72 + 8 * g;
        const u16* paw = Bs + i * 72 + 8 * g;
#pragma unroll
        for (int ks = 0; ks < 2; ++ks) {
            const bf16x8 b0 = *(const bf16x8*)(pbt + ks * 32);
            const bf16x8 b1 = *(const bf16x8*)(pbt + 16 * 72 + ks * 32);
#pragma unroll
            for (int a = 0; a < 12; ++a) {
                const bf16x8 av = *(const bf16x8*)(paw + a * 16 * 72 + ks * 32);
                acc[a][0] = __builtin_amdgcn_mfma_f32_16x16x32_bf16(av, b0, acc[a][0], 0, 0, 0);
                acc[a][1] = __builtin_amdgcn_mfma_f32_16x16x32_bf16(av, b1, acc[a][1], 0, 0, 0);
            }
        }
        __syncthreads();
    }
#pragma unroll
    for (int tt = 0; tt < 2; ++tt) {
        const int m = m0 + wave * 32 + 16 * tt + i;
        const float* x2r = x2 + (size_t)m * C_DIM;
        float* orow = out + (size_t)m * C_DIM;
#pragma unroll
        for (int a = 0; a < 12; ++a) {
            const int n0 = 16 * a + 4 * g;
            const float4 xv = *(const float4*)(x2r + n0);
            const float4 bi = *(const float4*)(f2b + n0);
            float4 rr;
            rr.x = xv.x + bi.x + acc[a][tt][0];
            rr.y = xv.y + bi.y + acc[a][tt][1];
            rr.z = xv.z + bi.z + acc[a][tt][2];
            rr.w = xv.w + bi.w + acc[a][tt][3];
            *(float4*)(orow + n0) = rr;
        }
    }
}

// ---------------------------------------------------------------------------
// orchestration. ws (PB = 48MB): [0,PB) xw->o ; [PB,2PB) q ; [2PB,3PB) k ;
// [3PB,4PB) v ; h overlays [PB,5PB) after attn ; x2n [5PB,6PB) ; weights at 6PB.
// x2 = d_out fp32.
// ---------------------------------------------------------------------------
static void run_block(const float* X, float* XOUT,
                      const float* g1, const float* b1, const float* qb,
                      const float* rpb, const float* pb,
                      const float* g2, const float* b2,
                      const float* f1b, const float* f2b,
                      const u16* qwT, const u16* pwT, const u16* f1wT, const u16* f2wT,
                      int shifted, char* ws, hipStream_t stream) {
    const size_t PB = (size_t)L_TOK * C_DIM * sizeof(u16);  // 48 MB
    u16* xw  = (u16*)ws;
    u16* q   = (u16*)(ws + PB);
    u16* k   = (u16*)(ws + 2 * PB);
    u16* v   = (u16*)(ws + 3 * PB);
    u16* o   = xw;
    u16* h   = (u16*)(ws + PB);          // [PB,5PB): L x 768 bf16, overlays q,k,v
    u16* x2n = (u16*)(ws + 5 * PB);
    float* x2 = XOUT;

    ln_kernel<<<L_TOK / 4, 256, 0, stream>>>(X, g1, b1, xw, shifted ? 1 : 0);
    qkv_mfma<<<L_TOK / 128, 256, 0, stream>>>(xw, qwT, qb, q, k, v);
    attn_mfma<<<NWIN * 6, 256, 0, stream>>>(q, k, v, rpb, o, shifted);
    proj_ln_mfma<<<L_TOK / 128, 256, 0, stream>>>(o, pwT, pb, X, g2, b2, x2, x2n, shifted);
    fc1_mfma<<<L_TOK / 128, 256, 0, stream>>>(x2n, f1wT, f1b, h);
    fc2_mfma<<<L_TOK / 128, 256, 0, stream>>>(h, f2wT, f2b, x2, XOUT);
}

extern "C" void kernel_launch(void* const* d_in, const int* in_sizes, int n_in,
                              void* d_out, int out_size, void* d_ws, size_t ws_size,
                              hipStream_t stream) {
    const float* x = (const float*)d_in[0];
    float* out = (float*)d_out;
    char* ws = (char*)d_ws;
    auto in = [&](int i) { return (const float*)d_in[i]; };

    const size_t offW = (size_t)L_TOK * C_DIM * sizeof(u16) * 6;
    u16* wbase = (u16*)(ws + offW);
    const size_t SQ = 110592, SP = 36864, SF1 = 147456, SF2 = 147456;
    const size_t WBLK = SQ + SP + SF1 + SF2;
    u16* qwT[2]  = { wbase,                    wbase + WBLK };
    u16* pwT[2]  = { wbase + SQ,               wbase + WBLK + SQ };
    u16* f1wT[2] = { wbase + SQ + SP,          wbase + WBLK + SQ + SP };
    u16* f2wT[2] = { wbase + SQ + SP + SF1,    wbase + WBLK + SQ + SP + SF1 };

    wtrans_kernel<<<(192 * 576 + 255) / 256, 256, 0, stream>>>(in(3),  qwT[0],  192, 576);
    wtrans_kernel<<<(192 * 192 + 255) / 256, 256, 0, stream>>>(in(6),  pwT[0],  192, 192);
    wtrans_kernel<<<(192 * 768 + 255) / 256, 256, 0, stream>>>(in(10), f1wT[0], 192, 768);
    wtrans_kernel<<<(768 * 192 + 255) / 256, 256, 0, stream>>>(in(12), f2wT[0], 768, 192);
    wtrans_kernel<<<(192 * 576 + 255) / 256, 256, 0, stream>>>(in(16), qwT[1],  192, 576);
    wtrans_kernel<<<(192 * 192 + 255) / 256, 256, 0, stream>>>(in(19), pwT[1],  192, 192);
    wtrans_kernel<<<(192 * 768 + 255) / 256, 256, 0, stream>>>(in(23), f1wT[1], 192, 768);
    wtrans_kernel<<<(768 * 192 + 255) / 256, 256, 0, stream>>>(in(25), f2wT[1], 768, 192);

    run_block(x, out, in(1), in(2), in(4), in(5), in(7), in(8), in(9), in(11), in(13),
              qwT[0], pwT[0], f1wT[0], f2wT[0], 0, ws, stream);
    run_block(out, out, in(14), in(15), in(17), in(18), in(20), in(21), in(22), in(24), in(26),
              qwT[1], pwT[1], f1wT[1], f2wT[1], 1, ws, stream);
}